// Round 1
// baseline (1762.186 us; speedup 1.0000x reference)
//
#include <hip/hip_runtime.h>
#include <hip/hip_bf16.h>
#include <math.h>

// ---- problem dims ----
#define B_    16
#define E_    384
#define P_    4096
#define NW_   64
#define S_    64
#define H_    12
#define DH_   32
#define HID_  1536
#define T_    65536
#define SHIFT_ 4

typedef unsigned short ushort_t;
typedef __attribute__((ext_vector_type(8))) __bf16 b8;
typedef __attribute__((ext_vector_type(4))) float f4;

__device__ __forceinline__ float u2f(ushort_t u){
    return __uint_as_float(((unsigned)u) << 16);
}
__device__ __forceinline__ ushort_t f2u(float f){
    union { __hip_bfloat16 h; ushort_t u; } cv;
    cv.h = __float2bfloat16(f);
    return cv.u;
}
__device__ __forceinline__ unsigned pack2(float lo, float hi){
    return (unsigned)f2u(lo) | ((unsigned)f2u(hi) << 16);
}
__device__ __forceinline__ float gelu_f(float v){
    return 0.5f * v * (1.0f + erff(v * 0.70710678118654752440f));
}

#define MFMA(a,b,c) __builtin_amdgcn_mfma_f32_16x16x32_bf16((a),(b),(c),0,0,0)

// =====================================================================
// WT: transpose f32 [K][N] -> bf16 [N][K]
// =====================================================================
__global__ __launch_bounds__(256) void wt_kernel(
    const float* __restrict__ src, ushort_t* __restrict__ dst, int K, int N)
{
    __shared__ float t[32][33];
    const int k0 = blockIdx.x * 32, n0 = blockIdx.y * 32;
    const int c = threadIdx.x & 31, r = threadIdx.x >> 5;
    for (int rr = r; rr < 32; rr += 8)
        t[rr][c] = src[(size_t)(k0 + rr) * N + n0 + c];
    __syncthreads();
    for (int rr = r; rr < 32; rr += 8)
        dst[(size_t)(n0 + rr) * K + k0 + c] = f2u(t[c][rr]);
}

// =====================================================================
// K1: x (B,E,P) f32 -> xt bf16 (B,P,E) + LN1 -> shift -> window -> xw
// =====================================================================
__global__ __launch_bounds__(256) void k1_ln_window(
    const float* __restrict__ x, const float* __restrict__ g,
    const float* __restrict__ bt,
    ushort_t* __restrict__ xt, ushort_t* __restrict__ xw)
{
    __shared__ float tile[32][E_ + 1];
    __shared__ float mu_s[32], rs_s[32];
    const int b = blockIdx.y, p0 = blockIdx.x * 32, tid = threadIdx.x;

    {
        const int pj = tid & 31, er = tid >> 5;
        for (int e = er; e < E_; e += 8)
            tile[pj][e] = x[((size_t)b * E_ + e) * P_ + p0 + pj];
    }
    __syncthreads();
    {
        const int tok = tid >> 3, l8 = tid & 7;
        float s = 0.f, ss = 0.f;
        for (int e = l8; e < E_; e += 8){ const float v = tile[tok][e]; s += v; ss += v * v; }
        s += __shfl_xor(s, 1); ss += __shfl_xor(ss, 1);
        s += __shfl_xor(s, 2); ss += __shfl_xor(ss, 2);
        s += __shfl_xor(s, 4); ss += __shfl_xor(ss, 4);
        if (l8 == 0){
            const float mu = s / E_;
            mu_s[tok] = mu;
            rs_s[tok] = rsqrtf(ss / E_ - mu * mu + 1e-5f);
        }
    }
    __syncthreads();

    unsigned* xtu = (unsigned*)xt;
    unsigned* xwu = (unsigned*)xw;
    for (int it = 0; it < 24; ++it){
        const int idx = it * 256 + tid;
        const int pj = idx / 192, ep = idx - pj * 192;
        const int e  = ep * 2;
        const int p  = p0 + pj;
        const int d1 = p >> 6, d2 = p & 63;
        const int i_ = (d1 + 64 - SHIFT_) & 63;
        const int j_ = (d2 + 64 - SHIFT_) & 63;
        const int w  = ((i_ >> 3) << 3) + (j_ >> 3);
        const int sd = ((i_ & 7) << 3) + (j_ & 7);
        const size_t dstu = (((size_t)b * NW_ + w) * S_ + sd) * (E_ / 2);
        const size_t srcu = ((size_t)b * P_ + p) * (E_ / 2);
        const float v0 = tile[pj][e], v1 = tile[pj][e + 1];
        xtu[srcu + ep] = pack2(v0, v1);
        const float mu = mu_s[pj], rs = rs_s[pj];
        xwu[dstu + ep] = pack2((v0 - mu) * rs * g[e] + bt[e],
                               (v1 - mu) * rs * g[e + 1] + bt[e + 1]);
    }
}

// =====================================================================
// helper: QKV 16x32 GEMM for one head, wave-local (K=384)
// =====================================================================
__device__ __forceinline__ void qkv_gemm(const b8* Xreg, const ushort_t* Wt,
                                         int hb, int l15, int l4, f4& a0, f4& a1)
{
    a0 = (f4){0.f, 0.f, 0.f, 0.f};
    a1 = (f4){0.f, 0.f, 0.f, 0.f};
#pragma unroll
    for (int kb = 0; kb < 12; ++kb){
        b8 w0 = *(const b8*)(Wt + (size_t)(hb + l15) * E_ + kb * 32 + l4 * 8);
        b8 w1 = *(const b8*)(Wt + (size_t)(hb + 16 + l15) * E_ + kb * 32 + l4 * 8);
        a0 = MFMA(Xreg[kb], w0, a0);
        a1 = MFMA(Xreg[kb], w1, a1);
    }
}

// =====================================================================
// K2: MFMA attention megakernel. Block = (b,w), 4 waves x 16 rows.
// =====================================================================
__global__ __launch_bounds__(256, 2) void k2_attn(
    const ushort_t* __restrict__ xw,
    const ushort_t* __restrict__ Wqt, const float* __restrict__ bq,
    const ushort_t* __restrict__ Wkt, const float* __restrict__ bk,
    const ushort_t* __restrict__ Wvt, const float* __restrict__ bv,
    const ushort_t* __restrict__ Wot, const float* __restrict__ bo,
    const float* __restrict__ pb, const float* __restrict__ mk,
    ushort_t* __restrict__ xt)
{
    __shared__ __align__(16) ushort_t q_lds[64 * 40];   // rows 80B
    __shared__ __align__(16) ushort_t k_lds[64 * 40];
    __shared__ __align__(16) ushort_t vt_lds[32 * 72];  // [d][t], rows 144B
    __shared__ __align__(16) ushort_t P_lds[64 * 72];
    __shared__ __align__(16) ushort_t z_lds[64 * 384];  // swizzled 16B units

    const int w = blockIdx.x, b = blockIdx.y;
    const int tid = threadIdx.x, lane = tid & 63, wv = tid >> 6;
    const int l15 = lane & 15, l4 = lane >> 4;
    const float scale = 0.17677669529663687f;

    // wave's 16 window rows -> A-frags in registers (full K=384)
    b8 Xreg[12];
    {
        const size_t rbase = (((size_t)(b * NW_ + w)) * S_ + wv * 16 + l15) * E_;
#pragma unroll
        for (int kb = 0; kb < 12; ++kb)
            Xreg[kb] = *(const b8*)(xw + rbase + kb * 32 + l4 * 8);
    }

    for (int h = 0; h < H_; ++h){
        const int hb = h * DH_;
        // ---- QKV ----
        {
            f4 a0, a1;
            qkv_gemm(Xreg, Wqt, hb, l15, l4, a0, a1);
            const float b0 = bq[hb + l15], b1 = bq[hb + 16 + l15];
#pragma unroll
            for (int r = 0; r < 4; ++r){
                const int row = wv * 16 + l4 * 4 + r;
                q_lds[row * 40 + l15]      = f2u((a0[r] + b0) * scale);
                q_lds[row * 40 + 16 + l15] = f2u((a1[r] + b1) * scale);
            }
            qkv_gemm(Xreg, Wkt, hb, l15, l4, a0, a1);
            const float c0 = bk[hb + l15], c1 = bk[hb + 16 + l15];
#pragma unroll
            for (int r = 0; r < 4; ++r){
                const int row = wv * 16 + l4 * 4 + r;
                k_lds[row * 40 + l15]      = f2u(a0[r] + c0);
                k_lds[row * 40 + 16 + l15] = f2u(a1[r] + c1);
            }
            qkv_gemm(Xreg, Wvt, hb, l15, l4, a0, a1);
            const float d0 = bv[hb + l15], d1 = bv[hb + 16 + l15];
#pragma unroll
            for (int r = 0; r < 4; ++r){
                const int trow = wv * 16 + l4 * 4 + r;
                vt_lds[l15 * 72 + trow]        = f2u(a0[r] + d0);
                vt_lds[(16 + l15) * 72 + trow] = f2u(a1[r] + d1);
            }
        }
        __syncthreads();

        // ---- QK^T + bias + softmax ----
        {
            const b8 qfrag = *(const b8*)(&q_lds[(wv * 16 + l15) * 40 + l4 * 8]);
            f4 sacc[4];
#pragma unroll
            for (int nt = 0; nt < 4; ++nt){
                const b8 kfrag = *(const b8*)(&k_lds[(nt * 16 + l15) * 40 + l4 * 8]);
                f4 c = (f4){0.f, 0.f, 0.f, 0.f};
                c = MFMA(qfrag, kfrag, c);
                const int t = nt * 16 + l15;
#pragma unroll
                for (int r = 0; r < 4; ++r){
                    const int sw = wv * 16 + l4 * 4 + r;
                    c[r] += pb[((size_t)h * S_ + sw) * S_ + t]
                          + mk[((size_t)w * S_ + sw) * S_ + t];
                }
                sacc[nt] = c;
            }
#pragma unroll
            for (int r = 0; r < 4; ++r){
                float m = fmaxf(fmaxf(sacc[0][r], sacc[1][r]),
                                fmaxf(sacc[2][r], sacc[3][r]));
                m = fmaxf(m, __shfl_xor(m, 1));
                m = fmaxf(m, __shfl_xor(m, 2));
                m = fmaxf(m, __shfl_xor(m, 4));
                m = fmaxf(m, __shfl_xor(m, 8));
                float s = 0.f;
                float e0 = expf(sacc[0][r] - m), e1 = expf(sacc[1][r] - m);
                float e2 = expf(sacc[2][r] - m), e3 = expf(sacc[3][r] - m);
                s = e0 + e1 + e2 + e3;
                s += __shfl_xor(s, 1); s += __shfl_xor(s, 2);
                s += __shfl_xor(s, 4); s += __shfl_xor(s, 8);
                const float inv = 1.f / s;
                const int row = wv * 16 + l4 * 4 + r;
                P_lds[row * 72 +      l15] = f2u(e0 * inv);
                P_lds[row * 72 + 16 + l15] = f2u(e1 * inv);
                P_lds[row * 72 + 32 + l15] = f2u(e2 * inv);
                P_lds[row * 72 + 48 + l15] = f2u(e3 * inv);
            }
        }

        // ---- PV ----
        {
            f4 zacc[2];
#pragma unroll
            for (int nt = 0; nt < 2; ++nt) zacc[nt] = (f4){0.f, 0.f, 0.f, 0.f};
#pragma unroll
            for (int kb = 0; kb < 2; ++kb){
                const b8 pfrag = *(const b8*)(&P_lds[(wv * 16 + l15) * 72 + kb * 32 + l4 * 8]);
#pragma unroll
                for (int nt = 0; nt < 2; ++nt){
                    const b8 vfrag = *(const b8*)(&vt_lds[(nt * 16 + l15) * 72 + kb * 32 + l4 * 8]);
                    zacc[nt] = MFMA(pfrag, vfrag, zacc[nt]);
                }
            }
            // z -> swizzled z_lds
#pragma unroll
            for (int nt = 0; nt < 2; ++nt){
                const int col = hb + nt * 16 + l15;
#pragma unroll
                for (int r = 0; r < 4; ++r){
                    const int row = wv * 16 + l4 * 4 + r;
                    const int unit = (col >> 3) ^ (row & 7);
                    z_lds[row * 384 + unit * 8 + (col & 7)] = f2u(zacc[nt][r]);
                }
            }
        }
        __syncthreads();
    }

    // ---- Wo + window reverse + unshift + residual ----
    b8 zA[12];
    {
        const int row = wv * 16 + l15;
#pragma unroll
        for (int kb = 0; kb < 12; ++kb){
            const int unit = (kb * 4 + l4) ^ (row & 7);
            zA[kb] = *(const b8*)(&z_lds[row * 384 + unit * 8]);
        }
    }
    for (int nto = 0; nto < 24; ++nto){
        const int n = nto * 16 + l15;
        f4 acc = (f4){0.f, 0.f, 0.f, 0.f};
#pragma unroll
        for (int kb = 0; kb < 12; ++kb){
            const b8 wfrag = *(const b8*)(Wot + (size_t)n * E_ + kb * 32 + l4 * 8);
            acc = MFMA(zA[kb], wfrag, acc);
        }
        const float bias = bo[n];
#pragma unroll
        for (int r = 0; r < 4; ++r){
            const int sw = wv * 16 + l4 * 4 + r;
            const int d1 = ((w >> 3) * 8 + (sw >> 3) + SHIFT_) & 63;
            const int d2 = ((w & 7) * 8 + (sw & 7) + SHIFT_) & 63;
            const size_t idx = ((size_t)b * P_ + d1 * 64 + d2) * E_ + n;
            xt[idx] = f2u(u2f(xt[idx]) + acc[r] + bias);
        }
    }
}

// =====================================================================
// K3: wave-local fused MLP. Block = 128 rows, 8 waves x 16 rows.
// Each wave: LN2 -> Xreg (reg-resident A-frags), then 48 chunks of 32
// HID cols: GEMM1 (swapped MFMA -> C[n][m]) -> gelu -> 1KiB wave-private
// swizzled LDS bounce (layout fix, NO barriers) -> GEMM2 accumulate into
// acc2[24] (full N=384 for the wave's 16 rows). h never leaves the wave.
// =====================================================================
__global__ __launch_bounds__(512, 2) void k3_mlp(
    ushort_t* __restrict__ xt,
    const float* __restrict__ g2, const float* __restrict__ bt2,
    const ushort_t* __restrict__ Wm1t, const float* __restrict__ bm1,
    const ushort_t* __restrict__ Wm2t, const float* __restrict__ bm2)
{
    // [2 dbuf][8 waves][16 rows x 64B], swizzled in 16B units
    __shared__ __align__(16) unsigned char hscr[2 * 8 * 1024];
    const int tid = threadIdx.x, lane = tid & 63, wv = tid >> 6;
    const int l15 = lane & 15, l4 = lane >> 4;
    const int row = blockIdx.x * 128 + wv * 16 + l15;

    // ---- LN2 -> Xreg (A/B-frag layout, full K=384) ----
    b8 Xreg[12];
    {
        const ushort_t* rp = xt + (size_t)row * E_;
        float s = 0.f, ss = 0.f;
#pragma unroll
        for (int kb = 0; kb < 12; ++kb){
            Xreg[kb] = *(const b8*)(rp + kb * 32 + l4 * 8);
#pragma unroll
            for (int j = 0; j < 8; ++j){ const float v = (float)Xreg[kb][j]; s += v; ss += v * v; }
        }
        // 4 lanes (l4=0..3) share a row: reduce across lane bits 4,5
        s += __shfl_xor(s, 16); ss += __shfl_xor(ss, 16);
        s += __shfl_xor(s, 32); ss += __shfl_xor(ss, 32);
        const float mu = s * (1.f / E_);
        const float rs = rsqrtf(ss * (1.f / E_) - mu * mu + 1e-5f);
#pragma unroll
        for (int kb = 0; kb < 12; ++kb){
            const int e0 = kb * 32 + l4 * 8;
            const f4 ga = *(const f4*)(g2 + e0), gb = *(const f4*)(g2 + e0 + 4);
            const f4 ba = *(const f4*)(bt2 + e0), bb = *(const f4*)(bt2 + e0 + 4);
            union { b8 v; ushort_t u[8]; } xo;
#pragma unroll
            for (int j = 0; j < 4; ++j){
                xo.u[j]     = f2u(((float)Xreg[kb][j]     - mu) * rs * ga[j] + ba[j]);
                xo.u[4 + j] = f2u(((float)Xreg[kb][4 + j] - mu) * rs * gb[j] + bb[j]);
            }
            Xreg[kb] = xo.v;
        }
    }

    // wave-private swizzled scratch offsets (16B-unit XOR swizzle per row)
    const int sw = (l15 ^ (l15 >> 2)) & 3;
    char* scp = (char*)hscr + (wv << 10) + l15 * 64;
    const int off_w0 = (((l4 >> 1) ^ sw) << 4) + ((l4 & 1) << 3);          // cols [l4*4, +4)
    const int off_w1 = ((((l4 >> 1) | 2) ^ sw) << 4) + ((l4 & 1) << 3);    // cols [16+l4*4, +4)
    const int off_r  = ((l4 ^ sw) << 4);                                   // cols [l4*8, +8)

    const ushort_t* pW1 = Wm1t + (size_t)l15 * E_ + l4 * 8;
    const ushort_t* pW2 = Wm2t + (size_t)l15 * HID_ + l4 * 8;

    f4 acc2[24];
#pragma unroll
    for (int i = 0; i < 24; ++i) acc2[i] = (f4){0.f, 0.f, 0.f, 0.f};

    for (int c = 0; c < 48; ++c){
        const int n0 = c * 32;
        // ---- GEMM1: h[16 rows][32 cols], swapped -> C[n][m], 4 indep chains
        f4 ce0 = (f4){0.f,0.f,0.f,0.f}, co0 = ce0, ce1 = ce0, co1 = ce0;
        const ushort_t* q0 = pW1 + (size_t)n0 * E_;
        const ushort_t* q1 = q0 + (size_t)16 * E_;
#pragma unroll
        for (int kb = 0; kb < 12; kb += 2){
            ce0 = MFMA(*(const b8*)(q0 + kb * 32), Xreg[kb], ce0);
            ce1 = MFMA(*(const b8*)(q1 + kb * 32), Xreg[kb], ce1);
            co0 = MFMA(*(const b8*)(q0 + (kb + 1) * 32), Xreg[kb + 1], co0);
            co1 = MFMA(*(const b8*)(q1 + (kb + 1) * 32), Xreg[kb + 1], co1);
        }
        const f4 bb0 = *(const f4*)(bm1 + n0 + l4 * 4);
        const f4 bb1 = *(const f4*)(bm1 + n0 + 16 + l4 * 4);
        const f4 c0 = ce0 + co0, c1 = ce1 + co1;
        // gelu + pack (lane holds 4 consecutive cols of its own row) -> bounce
        char* sb = scp + ((c & 1) << 13);
        {
            uint2 w0, w1;
            w0.x = pack2(gelu_f(c0[0] + bb0[0]), gelu_f(c0[1] + bb0[1]));
            w0.y = pack2(gelu_f(c0[2] + bb0[2]), gelu_f(c0[3] + bb0[3]));
            w1.x = pack2(gelu_f(c1[0] + bb1[0]), gelu_f(c1[1] + bb1[1]));
            w1.y = pack2(gelu_f(c1[2] + bb1[2]), gelu_f(c1[3] + bb1[3]));
            *(uint2*)(sb + off_w0) = w0;
            *(uint2*)(sb + off_w1) = w1;
        }
        const b8 h8 = *(const b8*)(sb + off_r);   // A/B-frag layout for this chunk
        // ---- GEMM2: acc2 += Wm2t[n2-rows][chunk] . h, 24 indep accumulators
#pragma unroll
        for (int nt2 = 0; nt2 < 24; ++nt2)
            acc2[nt2] = MFMA(*(const b8*)(pW2 + (size_t)nt2 * 16 * HID_ + n0), h8, acc2[nt2]);
        // phase-lock the 8 waves so they share L1 weight lines (no data dep)
        __builtin_amdgcn_s_barrier();
    }

    // ---- epilogue: gelu + residual, packed b64 RMW ----
    ushort_t* px = xt + (size_t)row * E_;
#pragma unroll
    for (int nt2 = 0; nt2 < 24; ++nt2){
        const int nb = nt2 * 16 + l4 * 4;
        const f4 bb = *(const f4*)(bm2 + nb);
        const uint2 old = *(const uint2*)(px + nb);
        const float o0 = u2f((ushort_t)(old.x))       + gelu_f(acc2[nt2][0] + bb[0]);
        const float o1 = u2f((ushort_t)(old.x >> 16)) + gelu_f(acc2[nt2][1] + bb[1]);
        const float o2 = u2f((ushort_t)(old.y))       + gelu_f(acc2[nt2][2] + bb[2]);
        const float o3 = u2f((ushort_t)(old.y >> 16)) + gelu_f(acc2[nt2][3] + bb[3]);
        uint2 nw; nw.x = pack2(o0, o1); nw.y = pack2(o2, o3);
        *(uint2*)(px + nb) = nw;
    }
}

// =====================================================================
// K4: xt bf16 (B,P,E) -> out f32 (B,E,P)
// =====================================================================
__global__ __launch_bounds__(256) void k4_out(
    const ushort_t* __restrict__ xt, float* __restrict__ out)
{
    __shared__ float tile[32][33];
    const int b = blockIdx.z, p0 = blockIdx.x * 32, e0 = blockIdx.y * 32;
    const int tid = threadIdx.x, c = tid & 31, r = tid >> 5;
    for (int rr = r; rr < 32; rr += 8)
        tile[rr][c] = u2f(xt[((size_t)b * P_ + p0 + rr) * E_ + e0 + c]);
    __syncthreads();
    for (int rr = r; rr < 32; rr += 8)
        out[((size_t)b * E_ + e0 + rr) * P_ + p0 + c] = tile[c][rr];
}

// =====================================================================
extern "C" void kernel_launch(void* const* d_in, const int* in_sizes, int n_in,
                              void* d_out, int out_size, void* d_ws, size_t ws_size,
                              hipStream_t stream)
{
    const float* x      = (const float*)d_in[0];
    const float* mask   = (const float*)d_in[1];
    const float* ln1_g  = (const float*)d_in[2];
    const float* ln1_b  = (const float*)d_in[3];
    const float* Wq     = (const float*)d_in[4];
    const float* bq     = (const float*)d_in[5];
    const float* Wk     = (const float*)d_in[6];
    const float* bk     = (const float*)d_in[7];
    const float* Wv     = (const float*)d_in[8];
    const float* bv     = (const float*)d_in[9];
    const float* Wo     = (const float*)d_in[10];
    const float* bo     = (const float*)d_in[11];
    const float* pos_b  = (const float*)d_in[12];
    const float* ln2_g  = (const float*)d_in[13];
    const float* ln2_b  = (const float*)d_in[14];
    const float* Wm1    = (const float*)d_in[15];
    const float* bm1    = (const float*)d_in[16];
    const float* Wm2    = (const float*)d_in[17];
    const float* bm2    = (const float*)d_in[18];

    // d_ws: xt (bf16 residual stream), 50.3 MB (known-safe)
    ushort_t* xt = (ushort_t*)d_ws;
    // d_out staging (dead before k4 writes): xw + transposed bf16 weights
    ushort_t* scratch = (ushort_t*)d_out;
    ushort_t* xw   = scratch;                         // 25,165,824
    ushort_t* Wqt  = scratch + 25165824;
    ushort_t* Wkt  = Wqt  + E_ * E_;
    ushort_t* Wvt  = Wkt  + E_ * E_;
    ushort_t* Wot  = Wvt  + E_ * E_;
    ushort_t* Wm1t = Wot  + E_ * E_;
    ushort_t* Wm2t = Wm1t + E_ * HID_;

    // weight transposes (f32 [K][N] -> bf16 [N][K])
    wt_kernel<<<dim3(12, 12), 256, 0, stream>>>(Wq,  Wqt,  E_, E_);
    wt_kernel<<<dim3(12, 12), 256, 0, stream>>>(Wk,  Wkt,  E_, E_);
    wt_kernel<<<dim3(12, 12), 256, 0, stream>>>(Wv,  Wvt,  E_, E_);
    wt_kernel<<<dim3(12, 12), 256, 0, stream>>>(Wo,  Wot,  E_, E_);
    wt_kernel<<<dim3(12, 48), 256, 0, stream>>>(Wm1, Wm1t, E_, HID_);
    wt_kernel<<<dim3(48, 12), 256, 0, stream>>>(Wm2, Wm2t, HID_, E_);

    k1_ln_window<<<dim3(P_ / 32, B_), 256, 0, stream>>>(x, ln1_g, ln1_b, xt, xw);
    k2_attn<<<dim3(NW_, B_), 256, 0, stream>>>(xw, Wqt, bq, Wkt, bk, Wvt, bv,
                                               Wot, bo, pos_b, mask, xt);
    k3_mlp<<<T_ / 128, 512, 0, stream>>>(xt, ln2_g, ln2_b, Wm1t, bm1, Wm2t, bm2);
    k4_out<<<dim3(P_ / 32, E_ / 32, B_), 256, 0, stream>>>(xt, (float*)d_out);
}

// Round 2
// 998.123 us; speedup vs baseline: 1.7655x; 1.7655x over previous
//
#include <hip/hip_runtime.h>
#include <hip/hip_bf16.h>
#include <math.h>

// ---- problem dims ----
#define B_    16
#define E_    384
#define P_    4096
#define NW_   64
#define S_    64
#define H_    12
#define DH_   32
#define HID_  1536
#define T_    65536
#define SHIFT_ 4
#define MCH_  16384   // M-chunk rows for the unfused MLP

typedef unsigned short ushort_t;
typedef __attribute__((ext_vector_type(8))) __bf16 b8;
typedef __attribute__((ext_vector_type(4))) float f4;

__device__ __forceinline__ float u2f(ushort_t u){
    return __uint_as_float(((unsigned)u) << 16);
}
__device__ __forceinline__ ushort_t f2u(float f){
    union { __hip_bfloat16 h; ushort_t u; } cv;
    cv.h = __float2bfloat16(f);
    return cv.u;
}
__device__ __forceinline__ unsigned pack2(float lo, float hi){
    return (unsigned)f2u(lo) | ((unsigned)f2u(hi) << 16);
}
__device__ __forceinline__ float gelu_f(float v){
    return 0.5f * v * (1.0f + erff(v * 0.70710678118654752440f));
}

#define MFMA(a,b,c) __builtin_amdgcn_mfma_f32_16x16x32_bf16((a),(b),(c),0,0,0)

// async global->LDS, 16B per lane
#define GL2LDS(gp, lp) \
    __builtin_amdgcn_global_load_lds((const __attribute__((address_space(1))) void*)(gp), \
                                     (__attribute__((address_space(3))) void*)(lp), 16, 0, 0)

// =====================================================================
// WT: transpose f32 [K][N] -> bf16 [N][K]
// =====================================================================
__global__ __launch_bounds__(256) void wt_kernel(
    const float* __restrict__ src, ushort_t* __restrict__ dst, int K, int N)
{
    __shared__ float t[32][33];
    const int k0 = blockIdx.x * 32, n0 = blockIdx.y * 32;
    const int c = threadIdx.x & 31, r = threadIdx.x >> 5;
    for (int rr = r; rr < 32; rr += 8)
        t[rr][c] = src[(size_t)(k0 + rr) * N + n0 + c];
    __syncthreads();
    for (int rr = r; rr < 32; rr += 8)
        dst[(size_t)(n0 + rr) * K + k0 + c] = f2u(t[c][rr]);
}

// =====================================================================
// K1: x (B,E,P) f32 -> xt bf16 (B,P,E) + LN1 -> shift -> window -> xw
// =====================================================================
__global__ __launch_bounds__(256) void k1_ln_window(
    const float* __restrict__ x, const float* __restrict__ g,
    const float* __restrict__ bt,
    ushort_t* __restrict__ xt, ushort_t* __restrict__ xw)
{
    __shared__ float tile[32][E_ + 1];
    __shared__ float mu_s[32], rs_s[32];
    const int b = blockIdx.y, p0 = blockIdx.x * 32, tid = threadIdx.x;

    {
        const int pj = tid & 31, er = tid >> 5;
        for (int e = er; e < E_; e += 8)
            tile[pj][e] = x[((size_t)b * E_ + e) * P_ + p0 + pj];
    }
    __syncthreads();
    {
        const int tok = tid >> 3, l8 = tid & 7;
        float s = 0.f, ss = 0.f;
        for (int e = l8; e < E_; e += 8){ const float v = tile[tok][e]; s += v; ss += v * v; }
        s += __shfl_xor(s, 1); ss += __shfl_xor(ss, 1);
        s += __shfl_xor(s, 2); ss += __shfl_xor(ss, 2);
        s += __shfl_xor(s, 4); ss += __shfl_xor(ss, 4);
        if (l8 == 0){
            const float mu = s / E_;
            mu_s[tok] = mu;
            rs_s[tok] = rsqrtf(ss / E_ - mu * mu + 1e-5f);
        }
    }
    __syncthreads();

    unsigned* xtu = (unsigned*)xt;
    unsigned* xwu = (unsigned*)xw;
    for (int it = 0; it < 24; ++it){
        const int idx = it * 256 + tid;
        const int pj = idx / 192, ep = idx - pj * 192;
        const int e  = ep * 2;
        const int p  = p0 + pj;
        const int d1 = p >> 6, d2 = p & 63;
        const int i_ = (d1 + 64 - SHIFT_) & 63;
        const int j_ = (d2 + 64 - SHIFT_) & 63;
        const int w  = ((i_ >> 3) << 3) + (j_ >> 3);
        const int sd = ((i_ & 7) << 3) + (j_ & 7);
        const size_t dstu = (((size_t)b * NW_ + w) * S_ + sd) * (E_ / 2);
        const size_t srcu = ((size_t)b * P_ + p) * (E_ / 2);
        const float v0 = tile[pj][e], v1 = tile[pj][e + 1];
        xtu[srcu + ep] = pack2(v0, v1);
        const float mu = mu_s[pj], rs = rs_s[pj];
        xwu[dstu + ep] = pack2((v0 - mu) * rs * g[e] + bt[e],
                               (v1 - mu) * rs * g[e + 1] + bt[e + 1]);
    }
}

// =====================================================================
// helper: QKV 16x32 GEMM for one head, wave-local (K=384)
// =====================================================================
__device__ __forceinline__ void qkv_gemm(const b8* Xreg, const ushort_t* Wt,
                                         int hb, int l15, int l4, f4& a0, f4& a1)
{
    a0 = (f4){0.f, 0.f, 0.f, 0.f};
    a1 = (f4){0.f, 0.f, 0.f, 0.f};
#pragma unroll
    for (int kb = 0; kb < 12; ++kb){
        b8 w0 = *(const b8*)(Wt + (size_t)(hb + l15) * E_ + kb * 32 + l4 * 8);
        b8 w1 = *(const b8*)(Wt + (size_t)(hb + 16 + l15) * E_ + kb * 32 + l4 * 8);
        a0 = MFMA(Xreg[kb], w0, a0);
        a1 = MFMA(Xreg[kb], w1, a1);
    }
}

// =====================================================================
// K2: MFMA attention megakernel. Block = (b,w), 4 waves x 16 rows.
// =====================================================================
__global__ __launch_bounds__(256, 2) void k2_attn(
    const ushort_t* __restrict__ xw,
    const ushort_t* __restrict__ Wqt, const float* __restrict__ bq,
    const ushort_t* __restrict__ Wkt, const float* __restrict__ bk,
    const ushort_t* __restrict__ Wvt, const float* __restrict__ bv,
    const ushort_t* __restrict__ Wot, const float* __restrict__ bo,
    const float* __restrict__ pb, const float* __restrict__ mk,
    ushort_t* __restrict__ xt)
{
    __shared__ __align__(16) ushort_t q_lds[64 * 40];   // rows 80B
    __shared__ __align__(16) ushort_t k_lds[64 * 40];
    __shared__ __align__(16) ushort_t vt_lds[32 * 72];  // [d][t], rows 144B
    __shared__ __align__(16) ushort_t P_lds[64 * 72];
    __shared__ __align__(16) ushort_t z_lds[64 * 384];  // swizzled 16B units

    const int w = blockIdx.x, b = blockIdx.y;
    const int tid = threadIdx.x, lane = tid & 63, wv = tid >> 6;
    const int l15 = lane & 15, l4 = lane >> 4;
    const float scale = 0.17677669529663687f;

    // wave's 16 window rows -> A-frags in registers (full K=384)
    b8 Xreg[12];
    {
        const size_t rbase = (((size_t)(b * NW_ + w)) * S_ + wv * 16 + l15) * E_;
#pragma unroll
        for (int kb = 0; kb < 12; ++kb)
            Xreg[kb] = *(const b8*)(xw + rbase + kb * 32 + l4 * 8);
    }

    for (int h = 0; h < H_; ++h){
        const int hb = h * DH_;
        // ---- QKV ----
        {
            f4 a0, a1;
            qkv_gemm(Xreg, Wqt, hb, l15, l4, a0, a1);
            const float b0 = bq[hb + l15], b1 = bq[hb + 16 + l15];
#pragma unroll
            for (int r = 0; r < 4; ++r){
                const int row = wv * 16 + l4 * 4 + r;
                q_lds[row * 40 + l15]      = f2u((a0[r] + b0) * scale);
                q_lds[row * 40 + 16 + l15] = f2u((a1[r] + b1) * scale);
            }
            qkv_gemm(Xreg, Wkt, hb, l15, l4, a0, a1);
            const float c0 = bk[hb + l15], c1 = bk[hb + 16 + l15];
#pragma unroll
            for (int r = 0; r < 4; ++r){
                const int row = wv * 16 + l4 * 4 + r;
                k_lds[row * 40 + l15]      = f2u(a0[r] + c0);
                k_lds[row * 40 + 16 + l15] = f2u(a1[r] + c1);
            }
            qkv_gemm(Xreg, Wvt, hb, l15, l4, a0, a1);
            const float d0 = bv[hb + l15], d1 = bv[hb + 16 + l15];
#pragma unroll
            for (int r = 0; r < 4; ++r){
                const int trow = wv * 16 + l4 * 4 + r;
                vt_lds[l15 * 72 + trow]        = f2u(a0[r] + d0);
                vt_lds[(16 + l15) * 72 + trow] = f2u(a1[r] + d1);
            }
        }
        __syncthreads();

        // ---- QK^T + bias + softmax ----
        {
            const b8 qfrag = *(const b8*)(&q_lds[(wv * 16 + l15) * 40 + l4 * 8]);
            f4 sacc[4];
#pragma unroll
            for (int nt = 0; nt < 4; ++nt){
                const b8 kfrag = *(const b8*)(&k_lds[(nt * 16 + l15) * 40 + l4 * 8]);
                f4 c = (f4){0.f, 0.f, 0.f, 0.f};
                c = MFMA(qfrag, kfrag, c);
                const int t = nt * 16 + l15;
#pragma unroll
                for (int r = 0; r < 4; ++r){
                    const int sw = wv * 16 + l4 * 4 + r;
                    c[r] += pb[((size_t)h * S_ + sw) * S_ + t]
                          + mk[((size_t)w * S_ + sw) * S_ + t];
                }
                sacc[nt] = c;
            }
#pragma unroll
            for (int r = 0; r < 4; ++r){
                float m = fmaxf(fmaxf(sacc[0][r], sacc[1][r]),
                                fmaxf(sacc[2][r], sacc[3][r]));
                m = fmaxf(m, __shfl_xor(m, 1));
                m = fmaxf(m, __shfl_xor(m, 2));
                m = fmaxf(m, __shfl_xor(m, 4));
                m = fmaxf(m, __shfl_xor(m, 8));
                float s = 0.f;
                float e0 = expf(sacc[0][r] - m), e1 = expf(sacc[1][r] - m);
                float e2 = expf(sacc[2][r] - m), e3 = expf(sacc[3][r] - m);
                s = e0 + e1 + e2 + e3;
                s += __shfl_xor(s, 1); s += __shfl_xor(s, 2);
                s += __shfl_xor(s, 4); s += __shfl_xor(s, 8);
                const float inv = 1.f / s;
                const int row = wv * 16 + l4 * 4 + r;
                P_lds[row * 72 +      l15] = f2u(e0 * inv);
                P_lds[row * 72 + 16 + l15] = f2u(e1 * inv);
                P_lds[row * 72 + 32 + l15] = f2u(e2 * inv);
                P_lds[row * 72 + 48 + l15] = f2u(e3 * inv);
            }
        }

        // ---- PV ----
        {
            f4 zacc[2];
#pragma unroll
            for (int nt = 0; nt < 2; ++nt) zacc[nt] = (f4){0.f, 0.f, 0.f, 0.f};
#pragma unroll
            for (int kb = 0; kb < 2; ++kb){
                const b8 pfrag = *(const b8*)(&P_lds[(wv * 16 + l15) * 72 + kb * 32 + l4 * 8]);
#pragma unroll
                for (int nt = 0; nt < 2; ++nt){
                    const b8 vfrag = *(const b8*)(&vt_lds[(nt * 16 + l15) * 72 + kb * 32 + l4 * 8]);
                    zacc[nt] = MFMA(pfrag, vfrag, zacc[nt]);
                }
            }
            // z -> swizzled z_lds
#pragma unroll
            for (int nt = 0; nt < 2; ++nt){
                const int col = hb + nt * 16 + l15;
#pragma unroll
                for (int r = 0; r < 4; ++r){
                    const int row = wv * 16 + l4 * 4 + r;
                    const int unit = (col >> 3) ^ (row & 7);
                    z_lds[row * 384 + unit * 8 + (col & 7)] = f2u(zacc[nt][r]);
                }
            }
        }
        __syncthreads();
    }

    // ---- Wo + window reverse + unshift + residual ----
    b8 zA[12];
    {
        const int row = wv * 16 + l15;
#pragma unroll
        for (int kb = 0; kb < 12; ++kb){
            const int unit = (kb * 4 + l4) ^ (row & 7);
            zA[kb] = *(const b8*)(&z_lds[row * 384 + unit * 8]);
        }
    }
    for (int nto = 0; nto < 24; ++nto){
        const int n = nto * 16 + l15;
        f4 acc = (f4){0.f, 0.f, 0.f, 0.f};
#pragma unroll
        for (int kb = 0; kb < 12; ++kb){
            const b8 wfrag = *(const b8*)(Wot + (size_t)n * E_ + kb * 32 + l4 * 8);
            acc = MFMA(zA[kb], wfrag, acc);
        }
        const float bias = bo[n];
#pragma unroll
        for (int r = 0; r < 4; ++r){
            const int sw = wv * 16 + l4 * 4 + r;
            const int d1 = ((w >> 3) * 8 + (sw >> 3) + SHIFT_) & 63;
            const int d2 = ((w & 7) * 8 + (sw & 7) + SHIFT_) & 63;
            const size_t idx = ((size_t)b * P_ + d1 * 64 + d2) * E_ + n;
            xt[idx] = f2u(u2f(xt[idx]) + acc[r] + bias);
        }
    }
}

// =====================================================================
// MLP (unfused, m97-style GEMMs over M-chunks of 16384 rows)
// =====================================================================

// LN2 apply: xt chunk rows -> xn (chunk-local), bf16
__global__ __launch_bounds__(256) void ln2_apply(
    const ushort_t* __restrict__ xtc, const float* __restrict__ g2,
    const float* __restrict__ b2, ushort_t* __restrict__ xn)
{
    const int tid = threadIdx.x;
    const int lr = blockIdx.x * 64 + (tid >> 2), q = tid & 3;
    const ushort_t* rp = xtc + (size_t)lr * E_;
    b8 xv[12];
    float s = 0.f, ss = 0.f;
#pragma unroll
    for (int i = 0; i < 12; ++i){
        xv[i] = *(const b8*)(rp + q * 8 + i * 32);
#pragma unroll
        for (int j = 0; j < 8; ++j){ const float v = (float)xv[i][j]; s += v; ss += v * v; }
    }
    s += __shfl_xor(s, 1); ss += __shfl_xor(ss, 1);
    s += __shfl_xor(s, 2); ss += __shfl_xor(ss, 2);
    const float mu = s * (1.f / E_);
    const float rs = rsqrtf(ss * (1.f / E_) - mu * mu + 1e-5f);
    ushort_t* op = xn + (size_t)lr * E_;
#pragma unroll
    for (int i = 0; i < 12; ++i){
        const int e = q * 8 + i * 32;
        const f4 ga = *(const f4*)(g2 + e), gb = *(const f4*)(g2 + e + 4);
        const f4 ba = *(const f4*)(b2 + e), bb = *(const f4*)(b2 + e + 4);
        union { b8 v; unsigned u[4]; } o;
        o.u[0] = pack2(((float)xv[i][0] - mu) * rs * ga[0] + ba[0],
                       ((float)xv[i][1] - mu) * rs * ga[1] + ba[1]);
        o.u[1] = pack2(((float)xv[i][2] - mu) * rs * ga[2] + ba[2],
                       ((float)xv[i][3] - mu) * rs * ga[3] + ba[3]);
        o.u[2] = pack2(((float)xv[i][4] - mu) * rs * gb[0] + bb[0],
                       ((float)xv[i][5] - mu) * rs * gb[1] + bb[1]);
        o.u[3] = pack2(((float)xv[i][6] - mu) * rs * gb[2] + bb[2],
                       ((float)xv[i][7] - mu) * rs * gb[3] + bb[3]);
        *(b8*)(op + e) = o.v;
    }
}

// stage a 128x32 bf16 tile: global (row stride gs ushorts) -> LDS linear
__device__ __forceinline__ void stage_tile(const ushort_t* gsrc, int gs,
                                           ushort_t* ldst, int k0, int tid)
{
#pragma unroll
    for (int i = 0; i < 2; ++i){
        const int eid = i * 256 + tid;
        const int row = eid >> 2, kq = eid & 3;
        GL2LDS(gsrc + (size_t)row * gs + k0 + kq * 8, ldst + eid * 8);
    }
}

// GEMM1: h[m][n] = gelu(xn @ Wm1 + bm1), M=16384, N=1536, K=384
__global__ __launch_bounds__(256, 3) void mlp_gemm1(
    const ushort_t* __restrict__ xn, const ushort_t* __restrict__ Wm1t,
    const float* __restrict__ bm1, ushort_t* __restrict__ h)
{
    __shared__ __align__(16) ushort_t lds[16384];   // A dbuf 8K + B dbuf 8K (ushorts)
    const int tid = threadIdx.x, lane = tid & 63, wv = tid >> 6;
    const int l15 = lane & 15, l4 = lane >> 4;
    const int wr = wv >> 1, wc = wv & 1;
    const int n0 = blockIdx.x * 128;
    const size_t m0 = (size_t)blockIdx.y * 128;

    const ushort_t* Ag = xn + m0 * E_;
    const ushort_t* Bg = Wm1t + (size_t)n0 * E_;

    f4 acc[4][4];
#pragma unroll
    for (int i = 0; i < 4; ++i)
#pragma unroll
        for (int j = 0; j < 4; ++j) acc[i][j] = (f4){0.f, 0.f, 0.f, 0.f};

    stage_tile(Ag, E_, lds, 0, tid);
    stage_tile(Bg, E_, lds + 8192, 0, tid);
    __syncthreads();
    int buf = 0;
    for (int ks = 0; ks < 12; ++ks){
        if (ks < 11){
            stage_tile(Ag, E_, lds + (buf ^ 1) * 4096, (ks + 1) * 32, tid);
            stage_tile(Bg, E_, lds + 8192 + (buf ^ 1) * 4096, (ks + 1) * 32, tid);
        }
        const ushort_t* Al = lds + buf * 4096;
        const ushort_t* Bl = lds + 8192 + buf * 4096;
        b8 ax[4], aw[4];
#pragma unroll
        for (int f = 0; f < 4; ++f){
            ax[f] = *(const b8*)(Al + (wr * 64 + f * 16 + l15) * 32 + l4 * 8);
            aw[f] = *(const b8*)(Bl + (wc * 64 + f * 16 + l15) * 32 + l4 * 8);
        }
#pragma unroll
        for (int fm = 0; fm < 4; ++fm)
#pragma unroll
            for (int fn = 0; fn < 4; ++fn)
                acc[fm][fn] = MFMA(aw[fn], ax[fm], acc[fm][fn]);
        __syncthreads();
        buf ^= 1;
    }

    // epilogue: gelu+bias, per-wave LDS bounce [32][72], coalesced b128 store
    ushort_t* bounce = lds + wv * 2304;
    const int l8r = lane >> 3, l8c = lane & 7;
#pragma unroll
    for (int hh = 0; hh < 2; ++hh){
#pragma unroll
        for (int f2 = 0; f2 < 2; ++f2){
            const int fm = hh * 2 + f2;
#pragma unroll
            for (int fn = 0; fn < 4; ++fn){
                const f4 v = acc[fm][fn];
                const f4 bb = *(const f4*)(bm1 + n0 + wc * 64 + fn * 16 + l4 * 4);
                uint2 pk;
                pk.x = pack2(gelu_f(v[0] + bb[0]), gelu_f(v[1] + bb[1]));
                pk.y = pack2(gelu_f(v[2] + bb[2]), gelu_f(v[3] + bb[3]));
                *(uint2*)(bounce + (f2 * 16 + l15) * 72 + fn * 16 + l4 * 4) = pk;
            }
        }
#pragma unroll
        for (int i = 0; i < 4; ++i){
            const int br = i * 8 + l8r;
            const b8 hv = *(const b8*)(bounce + br * 72 + l8c * 8);
            *(b8*)(h + (m0 + wr * 64 + hh * 32 + br) * HID_ + n0 + wc * 64 + l8c * 8) = hv;
        }
    }
}

// GEMM2: xt += gelu(h @ Wm2 + bm2), M=16384, N=384, K=1536
__global__ __launch_bounds__(256, 3) void mlp_gemm2(
    const ushort_t* __restrict__ h, const ushort_t* __restrict__ Wm2t,
    const float* __restrict__ bm2, ushort_t* __restrict__ xtc)
{
    __shared__ __align__(16) ushort_t lds[16384];
    const int tid = threadIdx.x, lane = tid & 63, wv = tid >> 6;
    const int l15 = lane & 15, l4 = lane >> 4;
    const int wr = wv >> 1, wc = wv & 1;
    const int n0 = blockIdx.x * 128;
    const size_t m0 = (size_t)blockIdx.y * 128;

    const ushort_t* Ag = h + m0 * HID_;
    const ushort_t* Bg = Wm2t + (size_t)n0 * HID_;

    f4 acc[4][4];
#pragma unroll
    for (int i = 0; i < 4; ++i)
#pragma unroll
        for (int j = 0; j < 4; ++j) acc[i][j] = (f4){0.f, 0.f, 0.f, 0.f};

    stage_tile(Ag, HID_, lds, 0, tid);
    stage_tile(Bg, HID_, lds + 8192, 0, tid);
    __syncthreads();
    int buf = 0;
    for (int ks = 0; ks < 48; ++ks){
        if (ks < 47){
            stage_tile(Ag, HID_, lds + (buf ^ 1) * 4096, (ks + 1) * 32, tid);
            stage_tile(Bg, HID_, lds + 8192 + (buf ^ 1) * 4096, (ks + 1) * 32, tid);
        }
        const ushort_t* Al = lds + buf * 4096;
        const ushort_t* Bl = lds + 8192 + buf * 4096;
        b8 ax[4], aw[4];
#pragma unroll
        for (int f = 0; f < 4; ++f){
            ax[f] = *(const b8*)(Al + (wr * 64 + f * 16 + l15) * 32 + l4 * 8);
            aw[f] = *(const b8*)(Bl + (wc * 64 + f * 16 + l15) * 32 + l4 * 8);
        }
#pragma unroll
        for (int fm = 0; fm < 4; ++fm)
#pragma unroll
            for (int fn = 0; fn < 4; ++fn)
                acc[fm][fn] = MFMA(aw[fn], ax[fm], acc[fm][fn]);
        __syncthreads();
        buf ^= 1;
    }

    // epilogue: gelu+bias -> bounce, then packed residual RMW on xt
    ushort_t* bounce = lds + wv * 2304;
    const int l8r = lane >> 3, l8c = lane & 7;
#pragma unroll
    for (int hh = 0; hh < 2; ++hh){
#pragma unroll
        for (int f2 = 0; f2 < 2; ++f2){
            const int fm = hh * 2 + f2;
#pragma unroll
            for (int fn = 0; fn < 4; ++fn){
                const f4 v = acc[fm][fn];
                const f4 bb = *(const f4*)(bm2 + n0 + wc * 64 + fn * 16 + l4 * 4);
                uint2 pk;
                pk.x = pack2(gelu_f(v[0] + bb[0]), gelu_f(v[1] + bb[1]));
                pk.y = pack2(gelu_f(v[2] + bb[2]), gelu_f(v[3] + bb[3]));
                *(uint2*)(bounce + (f2 * 16 + l15) * 72 + fn * 16 + l4 * 4) = pk;
            }
        }
#pragma unroll
        for (int i = 0; i < 4; ++i){
            const int br = i * 8 + l8r;
            const b8 yv = *(const b8*)(bounce + br * 72 + l8c * 8);
            ushort_t* px = xtc + (m0 + wr * 64 + hh * 32 + br) * E_ + n0 + wc * 64 + l8c * 8;
            const b8 ov = *(const b8*)px;
            union { b8 v; unsigned u[4]; } o;
#pragma unroll
            for (int j = 0; j < 4; ++j){
                const float lo = (float)ov[2 * j]     + (float)yv[2 * j];
                const float hi = (float)ov[2 * j + 1] + (float)yv[2 * j + 1];
                o.u[j] = pack2(lo, hi);
            }
            *(b8*)px = o.v;
        }
    }
}

// =====================================================================
// K4: xt bf16 (B,P,E) -> out f32 (B,E,P)
// =====================================================================
__global__ __launch_bounds__(256) void k4_out(
    const ushort_t* __restrict__ xt, float* __restrict__ out)
{
    __shared__ float tile[32][33];
    const int b = blockIdx.z, p0 = blockIdx.x * 32, e0 = blockIdx.y * 32;
    const int tid = threadIdx.x, c = tid & 31, r = tid >> 5;
    for (int rr = r; rr < 32; rr += 8)
        tile[rr][c] = u2f(xt[((size_t)b * P_ + p0 + rr) * E_ + e0 + c]);
    __syncthreads();
    for (int rr = r; rr < 32; rr += 8)
        out[((size_t)b * E_ + e0 + rr) * P_ + p0 + c] = tile[c][rr];
}

// =====================================================================
extern "C" void kernel_launch(void* const* d_in, const int* in_sizes, int n_in,
                              void* d_out, int out_size, void* d_ws, size_t ws_size,
                              hipStream_t stream)
{
    const float* x      = (const float*)d_in[0];
    const float* mask   = (const float*)d_in[1];
    const float* ln1_g  = (const float*)d_in[2];
    const float* ln1_b  = (const float*)d_in[3];
    const float* Wq     = (const float*)d_in[4];
    const float* bq     = (const float*)d_in[5];
    const float* Wk     = (const float*)d_in[6];
    const float* bk     = (const float*)d_in[7];
    const float* Wv     = (const float*)d_in[8];
    const float* bv     = (const float*)d_in[9];
    const float* Wo     = (const float*)d_in[10];
    const float* bo     = (const float*)d_in[11];
    const float* pos_b  = (const float*)d_in[12];
    const float* ln2_g  = (const float*)d_in[13];
    const float* ln2_b  = (const float*)d_in[14];
    const float* Wm1    = (const float*)d_in[15];
    const float* bm1    = (const float*)d_in[16];
    const float* Wm2    = (const float*)d_in[17];
    const float* bm2    = (const float*)d_in[18];

    // d_ws: xt (bf16 residual stream), 50.3 MB (known-safe)
    ushort_t* xt = (ushort_t*)d_ws;
    // d_out staging (dead before k4 writes):
    //   [0, 25165824)            xw  (k2 input) -> reused as h (16384x1536 bf16, exact fit)
    //   [25165824, 26935296)     transposed bf16 weights
    //   [26935296, 33226752)     xn  (LN2 output, 16384x384 bf16 per chunk)
    ushort_t* scratch = (ushort_t*)d_out;
    ushort_t* xw   = scratch;
    ushort_t* Wqt  = scratch + 25165824;
    ushort_t* Wkt  = Wqt  + E_ * E_;
    ushort_t* Wvt  = Wkt  + E_ * E_;
    ushort_t* Wot  = Wvt  + E_ * E_;
    ushort_t* Wm1t = Wot  + E_ * E_;
    ushort_t* Wm2t = Wm1t + E_ * HID_;
    ushort_t* xn   = Wm2t + HID_ * E_;
    ushort_t* hbuf = xw;   // alias: xw is dead after k2

    // weight transposes (f32 [K][N] -> bf16 [N][K])
    wt_kernel<<<dim3(12, 12), 256, 0, stream>>>(Wq,  Wqt,  E_, E_);
    wt_kernel<<<dim3(12, 12), 256, 0, stream>>>(Wk,  Wkt,  E_, E_);
    wt_kernel<<<dim3(12, 12), 256, 0, stream>>>(Wv,  Wvt,  E_, E_);
    wt_kernel<<<dim3(12, 12), 256, 0, stream>>>(Wo,  Wot,  E_, E_);
    wt_kernel<<<dim3(12, 48), 256, 0, stream>>>(Wm1, Wm1t, E_, HID_);
    wt_kernel<<<dim3(48, 12), 256, 0, stream>>>(Wm2, Wm2t, HID_, E_);

    k1_ln_window<<<dim3(P_ / 32, B_), 256, 0, stream>>>(x, ln1_g, ln1_b, xt, xw);
    k2_attn<<<dim3(NW_, B_), 256, 0, stream>>>(xw, Wqt, bq, Wkt, bk, Wvt, bv,
                                               Wot, bo, pos_b, mask, xt);

    for (int mc = 0; mc < 4; ++mc){
        ushort_t* xtc = xt + (size_t)mc * MCH_ * E_;
        ln2_apply<<<MCH_ / 64, 256, 0, stream>>>(xtc, ln2_g, ln2_b, xn);
        mlp_gemm1<<<dim3(HID_ / 128, MCH_ / 128), 256, 0, stream>>>(xn, Wm1t, bm1, hbuf);
        mlp_gemm2<<<dim3(E_ / 128, MCH_ / 128), 256, 0, stream>>>(hbuf, Wm2t, bm2, xtc);
    }

    k4_out<<<dim3(P_ / 32, E_ / 32, B_), 256, 0, stream>>>(xt, (float*)d_out);
}

// Round 3
// 728.554 us; speedup vs baseline: 2.4187x; 1.3700x over previous
//
#include <hip/hip_runtime.h>
#include <hip/hip_bf16.h>
#include <math.h>

// ---- problem dims ----
#define B_    16
#define E_    384
#define P_    4096
#define NW_   64
#define S_    64
#define H_    12
#define DH_   32
#define HID_  1536
#define T_    65536
#define SHIFT_ 4
#define MCH_  16384   // M-chunk rows (4 batches)

typedef unsigned short ushort_t;
typedef __attribute__((ext_vector_type(8))) __bf16 b8;
typedef __attribute__((ext_vector_type(8))) ushort_t u8v;
typedef __attribute__((ext_vector_type(4))) float f4;

__device__ __forceinline__ float u2f(ushort_t u){
    return __uint_as_float(((unsigned)u) << 16);
}
__device__ __forceinline__ ushort_t f2u(float f){
    union { __hip_bfloat16 h; ushort_t u; } cv;
    cv.h = __float2bfloat16(f);
    return cv.u;
}
__device__ __forceinline__ unsigned pack2(float lo, float hi){
    return (unsigned)f2u(lo) | ((unsigned)f2u(hi) << 16);
}
__device__ __forceinline__ float gelu_f(float v){
    return 0.5f * v * (1.0f + erff(v * 0.70710678118654752440f));
}

#define MFMA(a,b,c) __builtin_amdgcn_mfma_f32_16x16x32_bf16((a),(b),(c),0,0,0)

// async global->LDS, 16B per lane (per-lane lds ptr must be uniform+lane*16)
#define GL2LDS(gp, lp) \
    __builtin_amdgcn_global_load_lds((const __attribute__((address_space(1))) void*)(gp), \
                                     (__attribute__((address_space(3))) void*)(lp), 16, 0, 0)

// =====================================================================
// WT: transpose f32 [K][N] -> bf16 [N][K], optional scale fold
// =====================================================================
__global__ __launch_bounds__(256) void wt_kernel(
    const float* __restrict__ src, ushort_t* __restrict__ dst, int K, int N,
    float scale)
{
    __shared__ float t[32][33];
    const int k0 = blockIdx.x * 32, n0 = blockIdx.y * 32;
    const int c = threadIdx.x & 31, r = threadIdx.x >> 5;
    for (int rr = r; rr < 32; rr += 8)
        t[rr][c] = src[(size_t)(k0 + rr) * N + n0 + c];
    __syncthreads();
    for (int rr = r; rr < 32; rr += 8)
        dst[(size_t)(n0 + rr) * K + k0 + c] = f2u(t[c][rr] * scale);
}

// concat bias: [bq*scale | bk | bv] -> f32[1152]
__global__ __launch_bounds__(128) void bias_cat(
    const float* __restrict__ bq, const float* __restrict__ bk,
    const float* __restrict__ bv, float* __restrict__ o)
{
    const int i = blockIdx.x * 128 + threadIdx.x;
    float v;
    if (i < 384)      v = bq[i] * 0.17677669529663687f;
    else if (i < 768) v = bk[i - 384];
    else              v = bv[i - 768];
    o[i] = v;
}

// =====================================================================
// K1: x (B,E,P) f32 -> xt bf16 (B,P,E) + LN1 -> shift -> window -> xw
// =====================================================================
__global__ __launch_bounds__(256) void k1_ln_window(
    const float* __restrict__ x, const float* __restrict__ g,
    const float* __restrict__ bt,
    ushort_t* __restrict__ xt, ushort_t* __restrict__ xw)
{
    __shared__ float tile[32][E_ + 1];
    __shared__ float mu_s[32], rs_s[32];
    const int b = blockIdx.y, p0 = blockIdx.x * 32, tid = threadIdx.x;

    {
        const int pj = tid & 31, er = tid >> 5;
        for (int e = er; e < E_; e += 8)
            tile[pj][e] = x[((size_t)b * E_ + e) * P_ + p0 + pj];
    }
    __syncthreads();
    {
        const int tok = tid >> 3, l8 = tid & 7;
        float s = 0.f, ss = 0.f;
        for (int e = l8; e < E_; e += 8){ const float v = tile[tok][e]; s += v; ss += v * v; }
        s += __shfl_xor(s, 1); ss += __shfl_xor(ss, 1);
        s += __shfl_xor(s, 2); ss += __shfl_xor(ss, 2);
        s += __shfl_xor(s, 4); ss += __shfl_xor(ss, 4);
        if (l8 == 0){
            const float mu = s / E_;
            mu_s[tok] = mu;
            rs_s[tok] = rsqrtf(ss / E_ - mu * mu + 1e-5f);
        }
    }
    __syncthreads();

    unsigned* xtu = (unsigned*)xt;
    unsigned* xwu = (unsigned*)xw;
    for (int it = 0; it < 24; ++it){
        const int idx = it * 256 + tid;
        const int pj = idx / 192, ep = idx - pj * 192;
        const int e  = ep * 2;
        const int p  = p0 + pj;
        const int d1 = p >> 6, d2 = p & 63;
        const int i_ = (d1 + 64 - SHIFT_) & 63;
        const int j_ = (d2 + 64 - SHIFT_) & 63;
        const int w  = ((i_ >> 3) << 3) + (j_ >> 3);
        const int sd = ((i_ & 7) << 3) + (j_ & 7);
        const size_t dstu = (((size_t)b * NW_ + w) * S_ + sd) * (E_ / 2);
        const size_t srcu = ((size_t)b * P_ + p) * (E_ / 2);
        const float v0 = tile[pj][e], v1 = tile[pj][e + 1];
        xtu[srcu + ep] = pack2(v0, v1);
        const float mu = mu_s[pj], rs = rs_s[pj];
        xwu[dstu + ep] = pack2((v0 - mu) * rs * g[e] + bt[e],
                               (v1 - mu) * rs * g[e + 1] + bt[e + 1]);
    }
}

// =====================================================================
// stage a 128x32 bf16 tile: global (row stride gs ushorts) -> LDS linear
// =====================================================================
__device__ __forceinline__ void stage_tile(const ushort_t* gsrc, int gs,
                                           ushort_t* ldst, int k0, int tid)
{
#pragma unroll
    for (int i = 0; i < 2; ++i){
        const int eid = i * 256 + tid;
        const int row = eid >> 2, kq = eid & 3;
        GL2LDS(gsrc + (size_t)row * gs + k0 + kq * 8, ldst + eid * 8);
    }
}

// =====================================================================
// gemm128: C = A[M][AS-K] @ Bm^T (Bm = [N][K] bf16) + bias, 128x128 tiles.
// MODE 0: store bf16            (qkv projection, scale pre-folded)
// MODE 1: gelu, store bf16      (mlp gemm1)
// MODE 2: gelu, residual RMW    (mlp gemm2)
// MODE 3: residual RMW with window-reverse row permutation (Wo)
// =====================================================================
template<int KST, int AS, int OS, int MODE>
__global__ __launch_bounds__(256, 3) void gemm128(
    const ushort_t* __restrict__ A, const ushort_t* __restrict__ Bm,
    const float* __restrict__ bias, ushort_t* __restrict__ out)
{
    __shared__ __align__(16) ushort_t lds[16384];
    const int tid = threadIdx.x, lane = tid & 63, wv = tid >> 6;
    const int l15 = lane & 15, l4 = lane >> 4;
    const int wr = wv >> 1, wc = wv & 1;
    const int n0 = blockIdx.x * 128;
    const size_t m0 = (size_t)blockIdx.y * 128;

    const ushort_t* Ag = A + m0 * AS;
    const ushort_t* Bg = Bm + (size_t)n0 * (KST * 32);

    f4 acc[4][4];
#pragma unroll
    for (int i = 0; i < 4; ++i)
#pragma unroll
        for (int j = 0; j < 4; ++j) acc[i][j] = (f4){0.f, 0.f, 0.f, 0.f};

    stage_tile(Ag, AS, lds, 0, tid);
    stage_tile(Bg, KST * 32, lds + 8192, 0, tid);
    __syncthreads();
    int buf = 0;
    for (int ks = 0; ks < KST; ++ks){
        if (ks < KST - 1){
            stage_tile(Ag, AS, lds + (buf ^ 1) * 4096, (ks + 1) * 32, tid);
            stage_tile(Bg, KST * 32, lds + 8192 + (buf ^ 1) * 4096, (ks + 1) * 32, tid);
        }
        const ushort_t* Al = lds + buf * 4096;
        const ushort_t* Bl = lds + 8192 + buf * 4096;
        b8 ax[4], aw[4];
#pragma unroll
        for (int f = 0; f < 4; ++f){
            ax[f] = *(const b8*)(Al + (wr * 64 + f * 16 + l15) * 32 + l4 * 8);
            aw[f] = *(const b8*)(Bl + (wc * 64 + f * 16 + l15) * 32 + l4 * 8);
        }
#pragma unroll
        for (int fm = 0; fm < 4; ++fm)
#pragma unroll
            for (int fn = 0; fn < 4; ++fn)
                acc[fm][fn] = MFMA(aw[fn], ax[fm], acc[fm][fn]);
        __syncthreads();
        buf ^= 1;
    }

    // epilogue via per-wave LDS bounce [32][72] -> coalesced b128
    ushort_t* bounce = lds + wv * 2304;
    const int l8r = lane >> 3, l8c = lane & 7;
#pragma unroll
    for (int hh = 0; hh < 2; ++hh){
#pragma unroll
        for (int f2 = 0; f2 < 2; ++f2){
            const int fm = hh * 2 + f2;
#pragma unroll
            for (int fn = 0; fn < 4; ++fn){
                const f4 v = acc[fm][fn];
                const f4 bb = *(const f4*)(bias + n0 + wc * 64 + fn * 16 + l4 * 4);
                uint2 pk;
                if (MODE == 1 || MODE == 2){
                    pk.x = pack2(gelu_f(v[0] + bb[0]), gelu_f(v[1] + bb[1]));
                    pk.y = pack2(gelu_f(v[2] + bb[2]), gelu_f(v[3] + bb[3]));
                } else {
                    pk.x = pack2(v[0] + bb[0], v[1] + bb[1]);
                    pk.y = pack2(v[2] + bb[2], v[3] + bb[3]);
                }
                *(uint2*)(bounce + (f2 * 16 + l15) * 72 + fn * 16 + l4 * 4) = pk;
            }
        }
#pragma unroll
        for (int i = 0; i < 4; ++i){
            const int br = i * 8 + l8r;
            const int grow = (int)m0 + wr * 64 + hh * 32 + br;
            const b8 yv = *(const b8*)(bounce + br * 72 + l8c * 8);
            size_t orow;
            if (MODE == 3){
                const int bl = grow >> 12, wn = (grow >> 6) & 63, sw = grow & 63;
                const int d1 = ((wn >> 3) * 8 + (sw >> 3) + SHIFT_) & 63;
                const int d2 = ((wn & 7) * 8 + (sw & 7) + SHIFT_) & 63;
                orow = ((size_t)bl << 12) + d1 * 64 + d2;
            } else {
                orow = (size_t)grow;
            }
            ushort_t* px = out + orow * OS + n0 + wc * 64 + l8c * 8;
            if (MODE >= 2){
                const b8 ov = *(const b8*)px;
                union { b8 v; unsigned u[4]; } o;
#pragma unroll
                for (int j = 0; j < 4; ++j)
                    o.u[j] = pack2((float)ov[2 * j] + (float)yv[2 * j],
                                   (float)ov[2 * j + 1] + (float)yv[2 * j + 1]);
                *(b8*)px = o.v;
            } else {
                *(b8*)px = yv;
            }
        }
    }
}

// =====================================================================
// K2b: attention core only. qkv [rows][1152] chunk-local (q|k|v, q scaled),
// block = (window, batch-in-chunk, head-group of 4). z [rows][384] out.
// =====================================================================
__global__ __launch_bounds__(256) void k2b_attn(
    const ushort_t* __restrict__ qkv,
    const float* __restrict__ pb, const float* __restrict__ mk,
    ushort_t* __restrict__ z)
{
    __shared__ __align__(16) ushort_t q_lds[64 * 32];
    __shared__ __align__(16) ushort_t k_lds[64 * 32];
    __shared__ __align__(16) ushort_t vt_lds[32 * 72];
    __shared__ __align__(16) ushort_t P_lds[64 * 72];

    const int w = blockIdx.x, bl = blockIdx.y, hz = blockIdx.z;
    const int tid = threadIdx.x, lane = tid & 63, wv = tid >> 6;
    const int l15 = lane & 15, l4 = lane >> 4;
    const int rowbase = (bl * NW_ + w) * S_;

    // staging geometry: LDS unit tid holds row=tid>>2, global quad (tid&3)^((row>>1)&3)
    const int srow = tid >> 2, sqp = tid & 3;
    const int sfq = sqp ^ ((srow >> 1) & 3);
    const ushort_t* gql = qkv + (size_t)(rowbase + srow) * 1152 + sfq * 8;
    const ushort_t* gvl = qkv + (size_t)(rowbase + srow) * 1152 + 768 + sqp * 8;

    for (int hi = 0; hi < 4; ++hi){
        const int h = hz * 4 + hi;
        const int hb = h * 32;
        // ---- stage Q,K (swizzled source -> linear LDS), V (reg -> [d][t]) ----
        GL2LDS(gql + hb, q_lds + tid * 8);
        GL2LDS(gql + 384 + hb, k_lds + tid * 8);
        {
            const u8v vv = *(const u8v*)(gvl + hb);
#pragma unroll
            for (int j = 0; j < 8; ++j)
                vt_lds[(sqp * 8 + j) * 72 + srow] = vv[j];
        }
        __syncthreads();

        // ---- QK^T + bias + softmax ----
        {
            const int qr = wv * 16 + l15;
            const int uq = qr * 4 + (l4 ^ ((qr >> 1) & 3));
            const b8 qfrag = *(const b8*)(&q_lds[uq * 8]);
            f4 sacc[4];
#pragma unroll
            for (int nt = 0; nt < 4; ++nt){
                const int kr = nt * 16 + l15;
                const int uk = kr * 4 + (l4 ^ ((kr >> 1) & 3));
                const b8 kfrag = *(const b8*)(&k_lds[uk * 8]);
                f4 c = (f4){0.f, 0.f, 0.f, 0.f};
                c = MFMA(qfrag, kfrag, c);
                const int t = nt * 16 + l15;
#pragma unroll
                for (int r = 0; r < 4; ++r){
                    const int sw = wv * 16 + l4 * 4 + r;
                    c[r] += pb[((size_t)h * S_ + sw) * S_ + t]
                          + mk[((size_t)w * S_ + sw) * S_ + t];
                }
                sacc[nt] = c;
            }
#pragma unroll
            for (int r = 0; r < 4; ++r){
                float m = fmaxf(fmaxf(sacc[0][r], sacc[1][r]),
                                fmaxf(sacc[2][r], sacc[3][r]));
                m = fmaxf(m, __shfl_xor(m, 1));
                m = fmaxf(m, __shfl_xor(m, 2));
                m = fmaxf(m, __shfl_xor(m, 4));
                m = fmaxf(m, __shfl_xor(m, 8));
                const float e0 = expf(sacc[0][r] - m), e1 = expf(sacc[1][r] - m);
                const float e2 = expf(sacc[2][r] - m), e3 = expf(sacc[3][r] - m);
                float s = e0 + e1 + e2 + e3;
                s += __shfl_xor(s, 1); s += __shfl_xor(s, 2);
                s += __shfl_xor(s, 4); s += __shfl_xor(s, 8);
                const float inv = 1.f / s;
                const int row = wv * 16 + l4 * 4 + r;
                P_lds[row * 72 +      l15] = f2u(e0 * inv);
                P_lds[row * 72 + 16 + l15] = f2u(e1 * inv);
                P_lds[row * 72 + 32 + l15] = f2u(e2 * inv);
                P_lds[row * 72 + 48 + l15] = f2u(e3 * inv);
            }
        }

        // ---- PV -> z global ----
        {
            f4 zacc[2];
#pragma unroll
            for (int nt = 0; nt < 2; ++nt) zacc[nt] = (f4){0.f, 0.f, 0.f, 0.f};
#pragma unroll
            for (int kb = 0; kb < 2; ++kb){
                const b8 pfrag = *(const b8*)(&P_lds[(wv * 16 + l15) * 72 + kb * 32 + l4 * 8]);
#pragma unroll
                for (int nt = 0; nt < 2; ++nt){
                    const b8 vfrag = *(const b8*)(&vt_lds[(nt * 16 + l15) * 72 + kb * 32 + l4 * 8]);
                    zacc[nt] = MFMA(pfrag, vfrag, zacc[nt]);
                }
            }
#pragma unroll
            for (int nt = 0; nt < 2; ++nt)
#pragma unroll
                for (int r = 0; r < 4; ++r){
                    const int row = wv * 16 + l4 * 4 + r;
                    z[(size_t)(rowbase + row) * E_ + hb + nt * 16 + l15] = f2u(zacc[nt][r]);
                }
        }
        __syncthreads();
    }
}

// =====================================================================
// LN2 apply: xt chunk rows -> xn (chunk-local), bf16
// =====================================================================
__global__ __launch_bounds__(256) void ln2_apply(
    const ushort_t* __restrict__ xtc, const float* __restrict__ g2,
    const float* __restrict__ b2, ushort_t* __restrict__ xn)
{
    const int tid = threadIdx.x;
    const int lr = blockIdx.x * 64 + (tid >> 2), q = tid & 3;
    const ushort_t* rp = xtc + (size_t)lr * E_;
    b8 xv[12];
    float s = 0.f, ss = 0.f;
#pragma unroll
    for (int i = 0; i < 12; ++i){
        xv[i] = *(const b8*)(rp + q * 8 + i * 32);
#pragma unroll
        for (int j = 0; j < 8; ++j){ const float v = (float)xv[i][j]; s += v; ss += v * v; }
    }
    s += __shfl_xor(s, 1); ss += __shfl_xor(ss, 1);
    s += __shfl_xor(s, 2); ss += __shfl_xor(ss, 2);
    const float mu = s * (1.f / E_);
    const float rs = rsqrtf(ss * (1.f / E_) - mu * mu + 1e-5f);
    ushort_t* op = xn + (size_t)lr * E_;
#pragma unroll
    for (int i = 0; i < 12; ++i){
        const int e = q * 8 + i * 32;
        const f4 ga = *(const f4*)(g2 + e), gb = *(const f4*)(g2 + e + 4);
        const f4 ba = *(const f4*)(b2 + e), bb = *(const f4*)(b2 + e + 4);
        union { b8 v; unsigned u[4]; } o;
        o.u[0] = pack2(((float)xv[i][0] - mu) * rs * ga[0] + ba[0],
                       ((float)xv[i][1] - mu) * rs * ga[1] + ba[1]);
        o.u[1] = pack2(((float)xv[i][2] - mu) * rs * ga[2] + ba[2],
                       ((float)xv[i][3] - mu) * rs * ga[3] + ba[3]);
        o.u[2] = pack2(((float)xv[i][4] - mu) * rs * gb[0] + bb[0],
                       ((float)xv[i][5] - mu) * rs * gb[1] + bb[1]);
        o.u[3] = pack2(((float)xv[i][6] - mu) * rs * gb[2] + bb[2],
                       ((float)xv[i][7] - mu) * rs * gb[3] + bb[3]);
        *(b8*)(op + e) = o.v;
    }
}

// =====================================================================
// K4: xt bf16 (B,P,E) -> out f32 (B,E,P)
// =====================================================================
__global__ __launch_bounds__(256) void k4_out(
    const ushort_t* __restrict__ xt, float* __restrict__ out)
{
    __shared__ float tile[32][33];
    const int b = blockIdx.z, p0 = blockIdx.x * 32, e0 = blockIdx.y * 32;
    const int tid = threadIdx.x, c = tid & 31, r = tid >> 5;
    for (int rr = r; rr < 32; rr += 8)
        tile[rr][c] = u2f(xt[((size_t)b * P_ + p0 + rr) * E_ + e0 + c]);
    __syncthreads();
    for (int rr = r; rr < 32; rr += 8)
        out[((size_t)b * E_ + e0 + rr) * P_ + p0 + c] = tile[c][rr];
}

// =====================================================================
extern "C" void kernel_launch(void* const* d_in, const int* in_sizes, int n_in,
                              void* d_out, int out_size, void* d_ws, size_t ws_size,
                              hipStream_t stream)
{
    const float* x      = (const float*)d_in[0];
    const float* mask   = (const float*)d_in[1];
    const float* ln1_g  = (const float*)d_in[2];
    const float* ln1_b  = (const float*)d_in[3];
    const float* Wq     = (const float*)d_in[4];
    const float* bq     = (const float*)d_in[5];
    const float* Wk     = (const float*)d_in[6];
    const float* bk     = (const float*)d_in[7];
    const float* Wv     = (const float*)d_in[8];
    const float* bv     = (const float*)d_in[9];
    const float* Wo     = (const float*)d_in[10];
    const float* bo     = (const float*)d_in[11];
    const float* pos_b  = (const float*)d_in[12];
    const float* ln2_g  = (const float*)d_in[13];
    const float* ln2_b  = (const float*)d_in[14];
    const float* Wm1    = (const float*)d_in[15];
    const float* bm1    = (const float*)d_in[16];
    const float* Wm2    = (const float*)d_in[17];
    const float* bm2    = (const float*)d_in[18];

    // d_ws: xt (bf16 residual stream), 50.3 MB (known-safe)
    ushort_t* xt = (ushort_t*)d_ws;
    // d_out scratch map (100.66 MB total, all dead before k4 writes):
    //   [0, 25165824)             xw (k2 input); per-chunk reused as z, then as hbuf
    //   [25165824, +442368)       Wqkvt  [1152][384] (q rows scaled)
    //   [+442368,  +147456)       Wot
    //   [..]                      Wm1t (589824), Wm2t (589824)
    //   [26935296, +18874368)     qkv chunk buffer (attention phase)
    //                             == xn (MLP phase, 6291456) — time-shared
    //   [45809664, +2304)         bqkv f32[1152]
    ushort_t* scratch = (ushort_t*)d_out;
    ushort_t* xw    = scratch;
    ushort_t* Wqkvt = scratch + 25165824;
    ushort_t* Wot   = Wqkvt + 1152 * E_;
    ushort_t* Wm1t  = Wot  + E_ * E_;
    ushort_t* Wm2t  = Wm1t + E_ * HID_;
    ushort_t* qkvb  = scratch + 26935296;
    ushort_t* xn    = scratch + 26935296;
    float*    bqkv  = (float*)(scratch + 45809664);
    ushort_t* hbuf  = xw;   // alias: xw fully dead after attention phase

    const float qscale = 0.17677669529663687f;

    // weight transposes (f32 [K][N] -> bf16 [N][K]); q-scale folded
    wt_kernel<<<dim3(12, 12), 256, 0, stream>>>(Wq, Wqkvt, E_, E_, qscale);
    wt_kernel<<<dim3(12, 12), 256, 0, stream>>>(Wk, Wqkvt + 384 * E_, E_, E_, 1.f);
    wt_kernel<<<dim3(12, 12), 256, 0, stream>>>(Wv, Wqkvt + 768 * E_, E_, E_, 1.f);
    wt_kernel<<<dim3(12, 12), 256, 0, stream>>>(Wo, Wot, E_, E_, 1.f);
    wt_kernel<<<dim3(12, 48), 256, 0, stream>>>(Wm1, Wm1t, E_, HID_, 1.f);
    wt_kernel<<<dim3(48, 12), 256, 0, stream>>>(Wm2, Wm2t, HID_, E_, 1.f);
    bias_cat<<<9, 128, 0, stream>>>(bq, bk, bv, bqkv);

    k1_ln_window<<<dim3(P_ / 32, B_), 256, 0, stream>>>(x, ln1_g, ln1_b, xt, xw);

    // ---- attention phase: 4 chunks of 4 batches ----
    for (int mc = 0; mc < 4; ++mc){
        ushort_t* xwc = xw + (size_t)mc * MCH_ * E_;   // input rows; becomes z after qkv
        // QKV projection: [16384][1152]
        gemm128<12, E_, 1152, 0><<<dim3(9, MCH_ / 128), 256, 0, stream>>>(
            xwc, Wqkvt, bqkv, qkvb);
        // attention core -> z (overwrites consumed xw chunk)
        k2b_attn<<<dim3(NW_, 4, 3), 256, 0, stream>>>(qkvb, pos_b, mask, xwc);
        // Wo + window reverse + residual into xt
        gemm128<12, E_, E_, 3><<<dim3(3, MCH_ / 128), 256, 0, stream>>>(
            xwc, Wot, bo, xt + (size_t)mc * MCH_ * E_);
    }

    // ---- MLP phase: 4 chunks of 16384 rows ----
    for (int mc = 0; mc < 4; ++mc){
        ushort_t* xtc = xt + (size_t)mc * MCH_ * E_;
        ln2_apply<<<MCH_ / 64, 256, 0, stream>>>(xtc, ln2_g, ln2_b, xn);
        gemm128<12, E_, HID_, 1><<<dim3(HID_ / 128, MCH_ / 128), 256, 0, stream>>>(
            xn, Wm1t, bm1, hbuf);
        gemm128<48, HID_, E_, 2><<<dim3(E_ / 128, MCH_ / 128), 256, 0, stream>>>(
            hbuf, Wm2t, bm2, xtc);
    }

    k4_out<<<dim3(P_ / 32, E_ / 32, B_), 256, 0, stream>>>(xt, (float*)d_out);
}

// Round 4
// 721.165 us; speedup vs baseline: 2.4435x; 1.0102x over previous
//
#include <hip/hip_runtime.h>
#include <hip/hip_bf16.h>
#include <math.h>

// ---- problem dims ----
#define B_    16
#define E_    384
#define P_    4096
#define NW_   64
#define S_    64
#define H_    12
#define DH_   32
#define HID_  1536
#define T_    65536
#define SHIFT_ 4
#define MCH_  16384   // M-chunk rows (4 batches)

typedef unsigned short ushort_t;
typedef __attribute__((ext_vector_type(8))) __bf16 b8;
typedef __attribute__((ext_vector_type(8))) ushort_t u8v;
typedef __attribute__((ext_vector_type(4))) float f4;
typedef __attribute__((ext_vector_type(4))) unsigned u32x4;

__device__ __forceinline__ float u2f(ushort_t u){
    return __uint_as_float(((unsigned)u) << 16);
}
__device__ __forceinline__ ushort_t f2u(float f){
    union { __hip_bfloat16 h; ushort_t u; } cv;
    cv.h = __float2bfloat16(f);
    return cv.u;
}
__device__ __forceinline__ unsigned pack2(float lo, float hi){
    return (unsigned)f2u(lo) | ((unsigned)f2u(hi) << 16);
}
__device__ __forceinline__ float gelu_f(float v){
    return 0.5f * v * (1.0f + erff(v * 0.70710678118654752440f));
}

#define MFMA(a,b,c) __builtin_amdgcn_mfma_f32_16x16x32_bf16((a),(b),(c),0,0,0)

// async global->LDS, 16B per lane (per-lane lds ptr must be uniform+lane*16)
#define GL2LDS(gp, lp) \
    __builtin_amdgcn_global_load_lds((const __attribute__((address_space(1))) void*)(gp), \
                                     (__attribute__((address_space(3))) void*)(lp), 16, 0, 0)

// =====================================================================
// WT: transpose f32 [K][N] -> bf16 [N][K], optional scale fold
// =====================================================================
__global__ __launch_bounds__(256) void wt_kernel(
    const float* __restrict__ src, ushort_t* __restrict__ dst, int K, int N,
    float scale)
{
    __shared__ float t[32][33];
    const int k0 = blockIdx.x * 32, n0 = blockIdx.y * 32;
    const int c = threadIdx.x & 31, r = threadIdx.x >> 5;
    for (int rr = r; rr < 32; rr += 8)
        t[rr][c] = src[(size_t)(k0 + rr) * N + n0 + c];
    __syncthreads();
    for (int rr = r; rr < 32; rr += 8)
        dst[(size_t)(n0 + rr) * K + k0 + c] = f2u(t[c][rr] * scale);
}

// concat bias: [bq*scale | bk | bv] -> f32[1152]
__global__ __launch_bounds__(128) void bias_cat(
    const float* __restrict__ bq, const float* __restrict__ bk,
    const float* __restrict__ bv, float* __restrict__ o)
{
    const int i = blockIdx.x * 128 + threadIdx.x;
    float v;
    if (i < 384)      v = bq[i] * 0.17677669529663687f;
    else if (i < 768) v = bk[i - 384];
    else              v = bv[i - 768];
    o[i] = v;
}

// =====================================================================
// K1: x (B,E,P) f32 -> xt bf16 (B,P,E) + LN1 -> shift -> window -> xw
// LN stats fused into the load pass (exact f32); tile held as bf16 with
// conflict-free stride 386; xt written as raw u32 pair copies.
// =====================================================================
__global__ __launch_bounds__(256) void k1_ln_window(
    const float* __restrict__ x, const float* __restrict__ g,
    const float* __restrict__ bt,
    ushort_t* __restrict__ xt, ushort_t* __restrict__ xw)
{
    __shared__ ushort_t tile[32][E_ + 2];        // bf16, stride 386 (1 mod 32 in u32)
    __shared__ float red[2][8][32];
    __shared__ float mu_s[32], rs_s[32];
    const int b = blockIdx.y, p0 = blockIdx.x * 32, tid = threadIdx.x;

    {
        const int pj = tid & 31, er = tid >> 5;
        float s = 0.f, ss = 0.f;
        for (int e = er; e < E_; e += 8){
            const float v = x[((size_t)b * E_ + e) * P_ + p0 + pj];
            tile[pj][e] = f2u(v);
            s += v; ss += v * v;
        }
        red[0][er][pj] = s;
        red[1][er][pj] = ss;
    }
    __syncthreads();
    if (tid < 32){
        float s = 0.f, ss = 0.f;
#pragma unroll
        for (int er = 0; er < 8; ++er){ s += red[0][er][tid]; ss += red[1][er][tid]; }
        const float mu = s / E_;
        mu_s[tid] = mu;
        rs_s[tid] = rsqrtf(ss / E_ - mu * mu + 1e-5f);
    }
    __syncthreads();

    unsigned* xtu = (unsigned*)xt;
    unsigned* xwu = (unsigned*)xw;
    for (int it = 0; it < 24; ++it){
        const int idx = it * 256 + tid;
        const int pj = idx / 192, ep = idx - pj * 192;
        const int e  = ep * 2;
        const int p  = p0 + pj;
        const int d1 = p >> 6, d2 = p & 63;
        const int i_ = (d1 + 64 - SHIFT_) & 63;
        const int j_ = (d2 + 64 - SHIFT_) & 63;
        const int w  = ((i_ >> 3) << 3) + (j_ >> 3);
        const int sd = ((i_ & 7) << 3) + (j_ & 7);
        const size_t dstu = (((size_t)b * NW_ + w) * S_ + sd) * (E_ / 2);
        const size_t srcu = ((size_t)b * P_ + p) * (E_ / 2);
        const unsigned tv = *(const unsigned*)&tile[pj][e];
        xtu[srcu + ep] = tv;                      // xt = bf16(v) pair, verbatim
        const float v0 = u2f((ushort_t)tv), v1 = u2f((ushort_t)(tv >> 16));
        const float mu = mu_s[pj], rs = rs_s[pj];
        xwu[dstu + ep] = pack2((v0 - mu) * rs * g[e] + bt[e],
                               (v1 - mu) * rs * g[e + 1] + bt[e + 1]);
    }
}

// =====================================================================
// stage a 128x32 bf16 tile: global (row stride gs ushorts) -> LDS linear
// =====================================================================
__device__ __forceinline__ void stage_tile(const ushort_t* gsrc, int gs,
                                           ushort_t* ldst, int k0, int tid)
{
#pragma unroll
    for (int i = 0; i < 2; ++i){
        const int eid = i * 256 + tid;
        const int row = eid >> 2, kq = eid & 3;
        GL2LDS(gsrc + (size_t)row * gs + k0 + kq * 8, ldst + eid * 8);
    }
}

// =====================================================================
// gemm128: C = A[M][AS-K] @ Bm^T (Bm = [N][K] bf16) + bias, 128x128 tiles.
// XCD-bijective block swizzle: same-A-panel blocks land on one XCD's L2.
// MODE 0: store bf16 nontemporal (qkv projection, scale pre-folded)
// MODE 1: gelu, store bf16 nontemporal (mlp gemm1)
// MODE 2: gelu, residual RMW            (mlp gemm2)
// MODE 3: residual RMW with window-reverse row permutation (Wo)
// =====================================================================
template<int KST, int AS, int OS, int MODE>
__global__ __launch_bounds__(256, 4) void gemm128(
    const ushort_t* __restrict__ A, const ushort_t* __restrict__ Bm,
    const float* __restrict__ bias, ushort_t* __restrict__ out)
{
    __shared__ __align__(16) ushort_t lds[16384];
    const int tid = threadIdx.x, lane = tid & 63, wv = tid >> 6;
    const int l15 = lane & 15, l4 = lane >> 4;
    const int wr = wv >> 1, wc = wv & 1;

    // XCD-aware bijective remap (all grids have nwg % 8 == 0)
    const int gx = gridDim.x;
    const int nwg = gx * gridDim.y;
    const int d = blockIdx.y * gx + blockIdx.x;
    const int cpx = nwg >> 3;
    const int lb = (d & 7) * cpx + (d >> 3);
    const int n0 = (lb % gx) * 128;
    const size_t m0 = (size_t)(lb / gx) * 128;

    const ushort_t* Ag = A + m0 * AS;
    const ushort_t* Bg = Bm + (size_t)n0 * (KST * 32);

    f4 acc[4][4];
#pragma unroll
    for (int i = 0; i < 4; ++i)
#pragma unroll
        for (int j = 0; j < 4; ++j) acc[i][j] = (f4){0.f, 0.f, 0.f, 0.f};

    stage_tile(Ag, AS, lds, 0, tid);
    stage_tile(Bg, KST * 32, lds + 8192, 0, tid);
    __syncthreads();
    int buf = 0;
    for (int ks = 0; ks < KST; ++ks){
        if (ks < KST - 1){
            stage_tile(Ag, AS, lds + (buf ^ 1) * 4096, (ks + 1) * 32, tid);
            stage_tile(Bg, KST * 32, lds + 8192 + (buf ^ 1) * 4096, (ks + 1) * 32, tid);
        }
        const ushort_t* Al = lds + buf * 4096;
        const ushort_t* Bl = lds + 8192 + buf * 4096;
        b8 ax[4], aw[4];
#pragma unroll
        for (int f = 0; f < 4; ++f){
            ax[f] = *(const b8*)(Al + (wr * 64 + f * 16 + l15) * 32 + l4 * 8);
            aw[f] = *(const b8*)(Bl + (wc * 64 + f * 16 + l15) * 32 + l4 * 8);
        }
#pragma unroll
        for (int fm = 0; fm < 4; ++fm)
#pragma unroll
            for (int fn = 0; fn < 4; ++fn)
                acc[fm][fn] = MFMA(aw[fn], ax[fm], acc[fm][fn]);
        __syncthreads();
        buf ^= 1;
    }

    // epilogue via per-wave LDS bounce [32][72] -> coalesced b128
    ushort_t* bounce = lds + wv * 2304;
    const int l8r = lane >> 3, l8c = lane & 7;
#pragma unroll
    for (int hh = 0; hh < 2; ++hh){
#pragma unroll
        for (int f2 = 0; f2 < 2; ++f2){
            const int fm = hh * 2 + f2;
#pragma unroll
            for (int fn = 0; fn < 4; ++fn){
                const f4 v = acc[fm][fn];
                const f4 bb = *(const f4*)(bias + n0 + wc * 64 + fn * 16 + l4 * 4);
                uint2 pk;
                if (MODE == 1 || MODE == 2){
                    pk.x = pack2(gelu_f(v[0] + bb[0]), gelu_f(v[1] + bb[1]));
                    pk.y = pack2(gelu_f(v[2] + bb[2]), gelu_f(v[3] + bb[3]));
                } else {
                    pk.x = pack2(v[0] + bb[0], v[1] + bb[1]);
                    pk.y = pack2(v[2] + bb[2], v[3] + bb[3]);
                }
                *(uint2*)(bounce + (f2 * 16 + l15) * 72 + fn * 16 + l4 * 4) = pk;
            }
        }
#pragma unroll
        for (int i = 0; i < 4; ++i){
            const int br = i * 8 + l8r;
            const int grow = (int)m0 + wr * 64 + hh * 32 + br;
            const b8 yv = *(const b8*)(bounce + br * 72 + l8c * 8);
            size_t orow;
            if (MODE == 3){
                const int bl = grow >> 12, wn = (grow >> 6) & 63, sw = grow & 63;
                const int d1 = ((wn >> 3) * 8 + (sw >> 3) + SHIFT_) & 63;
                const int d2 = ((wn & 7) * 8 + (sw & 7) + SHIFT_) & 63;
                orow = ((size_t)bl << 12) + d1 * 64 + d2;
            } else {
                orow = (size_t)grow;
            }
            ushort_t* px = out + orow * OS + n0 + wc * 64 + l8c * 8;
            if (MODE >= 2){
                const b8 ov = *(const b8*)px;
                union { b8 v; unsigned u[4]; } o;
#pragma unroll
                for (int j = 0; j < 4; ++j)
                    o.u[j] = pack2((float)ov[2 * j] + (float)yv[2 * j],
                                   (float)ov[2 * j + 1] + (float)yv[2 * j + 1]);
                *(b8*)px = o.v;
            } else {
                // streaming output: don't evict the operand panels from L2
                union { b8 v; u32x4 q; } t; t.v = yv;
                __builtin_nontemporal_store(t.q, (u32x4*)px);
            }
        }
    }
}

// =====================================================================
// K2b: attention core only. qkv [rows][1152] chunk-local (q|k|v, q scaled),
// block = (window, batch-in-chunk, head-group of 4). z [rows][384] out.
// =====================================================================
__global__ __launch_bounds__(256) void k2b_attn(
    const ushort_t* __restrict__ qkv,
    const float* __restrict__ pb, const float* __restrict__ mk,
    ushort_t* __restrict__ z)
{
    __shared__ __align__(16) ushort_t q_lds[64 * 32];
    __shared__ __align__(16) ushort_t k_lds[64 * 32];
    __shared__ __align__(16) ushort_t vt_lds[32 * 72];
    __shared__ __align__(16) ushort_t P_lds[64 * 72];

    const int w = blockIdx.x, bl = blockIdx.y, hz = blockIdx.z;
    const int tid = threadIdx.x, lane = tid & 63, wv = tid >> 6;
    const int l15 = lane & 15, l4 = lane >> 4;
    const int rowbase = (bl * NW_ + w) * S_;

    // staging geometry: LDS unit tid holds row=tid>>2, global quad (tid&3)^((row>>1)&3)
    const int srow = tid >> 2, sqp = tid & 3;
    const int sfq = sqp ^ ((srow >> 1) & 3);
    const ushort_t* gql = qkv + (size_t)(rowbase + srow) * 1152 + sfq * 8;
    const ushort_t* gvl = qkv + (size_t)(rowbase + srow) * 1152 + 768 + sqp * 8;

    for (int hi = 0; hi < 4; ++hi){
        const int h = hz * 4 + hi;
        const int hb = h * 32;
        // ---- stage Q,K (swizzled source -> linear LDS), V (reg -> [d][t]) ----
        GL2LDS(gql + hb, q_lds + tid * 8);
        GL2LDS(gql + 384 + hb, k_lds + tid * 8);
        {
            const u8v vv = *(const u8v*)(gvl + hb);
#pragma unroll
            for (int j = 0; j < 8; ++j)
                vt_lds[(sqp * 8 + j) * 72 + srow] = vv[j];
        }
        __syncthreads();

        // ---- QK^T + bias + softmax ----
        {
            const int qr = wv * 16 + l15;
            const int uq = qr * 4 + (l4 ^ ((qr >> 1) & 3));
            const b8 qfrag = *(const b8*)(&q_lds[uq * 8]);
            f4 sacc[4];
#pragma unroll
            for (int nt = 0; nt < 4; ++nt){
                const int kr = nt * 16 + l15;
                const int uk = kr * 4 + (l4 ^ ((kr >> 1) & 3));
                const b8 kfrag = *(const b8*)(&k_lds[uk * 8]);
                f4 c = (f4){0.f, 0.f, 0.f, 0.f};
                c = MFMA(qfrag, kfrag, c);
                const int t = nt * 16 + l15;
#pragma unroll
                for (int r = 0; r < 4; ++r){
                    const int sw = wv * 16 + l4 * 4 + r;
                    c[r] += pb[((size_t)h * S_ + sw) * S_ + t]
                          + mk[((size_t)w * S_ + sw) * S_ + t];
                }
                sacc[nt] = c;
            }
#pragma unroll
            for (int r = 0; r < 4; ++r){
                float m = fmaxf(fmaxf(sacc[0][r], sacc[1][r]),
                                fmaxf(sacc[2][r], sacc[3][r]));
                m = fmaxf(m, __shfl_xor(m, 1));
                m = fmaxf(m, __shfl_xor(m, 2));
                m = fmaxf(m, __shfl_xor(m, 4));
                m = fmaxf(m, __shfl_xor(m, 8));
                const float e0 = expf(sacc[0][r] - m), e1 = expf(sacc[1][r] - m);
                const float e2 = expf(sacc[2][r] - m), e3 = expf(sacc[3][r] - m);
                float s = e0 + e1 + e2 + e3;
                s += __shfl_xor(s, 1); s += __shfl_xor(s, 2);
                s += __shfl_xor(s, 4); s += __shfl_xor(s, 8);
                const float inv = 1.f / s;
                const int row = wv * 16 + l4 * 4 + r;
                P_lds[row * 72 +      l15] = f2u(e0 * inv);
                P_lds[row * 72 + 16 + l15] = f2u(e1 * inv);
                P_lds[row * 72 + 32 + l15] = f2u(e2 * inv);
                P_lds[row * 72 + 48 + l15] = f2u(e3 * inv);
            }
        }

        // ---- PV -> z global ----
        {
            f4 zacc[2];
#pragma unroll
            for (int nt = 0; nt < 2; ++nt) zacc[nt] = (f4){0.f, 0.f, 0.f, 0.f};
#pragma unroll
            for (int kb = 0; kb < 2; ++kb){
                const b8 pfrag = *(const b8*)(&P_lds[(wv * 16 + l15) * 72 + kb * 32 + l4 * 8]);
#pragma unroll
                for (int nt = 0; nt < 2; ++nt){
                    const b8 vfrag = *(const b8*)(&vt_lds[(nt * 16 + l15) * 72 + kb * 32 + l4 * 8]);
                    zacc[nt] = MFMA(pfrag, vfrag, zacc[nt]);
                }
            }
#pragma unroll
            for (int nt = 0; nt < 2; ++nt)
#pragma unroll
                for (int r = 0; r < 4; ++r){
                    const int row = wv * 16 + l4 * 4 + r;
                    z[(size_t)(rowbase + row) * E_ + hb + nt * 16 + l15] = f2u(zacc[nt][r]);
                }
        }
        __syncthreads();
    }
}

// =====================================================================
// LN2 apply: xt chunk rows -> xn (chunk-local), bf16
// =====================================================================
__global__ __launch_bounds__(256) void ln2_apply(
    const ushort_t* __restrict__ xtc, const float* __restrict__ g2,
    const float* __restrict__ b2, ushort_t* __restrict__ xn)
{
    const int tid = threadIdx.x;
    const int lr = blockIdx.x * 64 + (tid >> 2), q = tid & 3;
    const ushort_t* rp = xtc + (size_t)lr * E_;
    b8 xv[12];
    float s = 0.f, ss = 0.f;
#pragma unroll
    for (int i = 0; i < 12; ++i){
        xv[i] = *(const b8*)(rp + q * 8 + i * 32);
#pragma unroll
        for (int j = 0; j < 8; ++j){ const float v = (float)xv[i][j]; s += v; ss += v * v; }
    }
    s += __shfl_xor(s, 1); ss += __shfl_xor(ss, 1);
    s += __shfl_xor(s, 2); ss += __shfl_xor(ss, 2);
    const float mu = s * (1.f / E_);
    const float rs = rsqrtf(ss * (1.f / E_) - mu * mu + 1e-5f);
    ushort_t* op = xn + (size_t)lr * E_;
#pragma unroll
    for (int i = 0; i < 12; ++i){
        const int e = q * 8 + i * 32;
        const f4 ga = *(const f4*)(g2 + e), gb = *(const f4*)(g2 + e + 4);
        const f4 ba = *(const f4*)(b2 + e), bb = *(const f4*)(b2 + e + 4);
        union { b8 v; unsigned u[4]; } o;
        o.u[0] = pack2(((float)xv[i][0] - mu) * rs * ga[0] + ba[0],
                       ((float)xv[i][1] - mu) * rs * ga[1] + ba[1]);
        o.u[1] = pack2(((float)xv[i][2] - mu) * rs * ga[2] + ba[2],
                       ((float)xv[i][3] - mu) * rs * ga[3] + ba[3]);
        o.u[2] = pack2(((float)xv[i][4] - mu) * rs * gb[0] + bb[0],
                       ((float)xv[i][5] - mu) * rs * gb[1] + bb[1]);
        o.u[3] = pack2(((float)xv[i][6] - mu) * rs * gb[2] + bb[2],
                       ((float)xv[i][7] - mu) * rs * gb[3] + bb[3]);
        *(b8*)(op + e) = o.v;
    }
}

// =====================================================================
// K4: xt bf16 (B,P,E) -> out f32 (B,E,P), nontemporal stores
// =====================================================================
__global__ __launch_bounds__(256) void k4_out(
    const ushort_t* __restrict__ xt, float* __restrict__ out)
{
    __shared__ float tile[32][33];
    const int b = blockIdx.z, p0 = blockIdx.x * 32, e0 = blockIdx.y * 32;
    const int tid = threadIdx.x, c = tid & 31, r = tid >> 5;
    for (int rr = r; rr < 32; rr += 8)
        tile[rr][c] = u2f(xt[((size_t)b * P_ + p0 + rr) * E_ + e0 + c]);
    __syncthreads();
    for (int rr = r; rr < 32; rr += 8)
        __builtin_nontemporal_store(tile[c][rr],
            &out[((size_t)b * E_ + e0 + rr) * P_ + p0 + c]);
}

// =====================================================================
extern "C" void kernel_launch(void* const* d_in, const int* in_sizes, int n_in,
                              void* d_out, int out_size, void* d_ws, size_t ws_size,
                              hipStream_t stream)
{
    const float* x      = (const float*)d_in[0];
    const float* mask   = (const float*)d_in[1];
    const float* ln1_g  = (const float*)d_in[2];
    const float* ln1_b  = (const float*)d_in[3];
    const float* Wq     = (const float*)d_in[4];
    const float* bq     = (const float*)d_in[5];
    const float* Wk     = (const float*)d_in[6];
    const float* bk     = (const float*)d_in[7];
    const float* Wv     = (const float*)d_in[8];
    const float* bv     = (const float*)d_in[9];
    const float* Wo     = (const float*)d_in[10];
    const float* bo     = (const float*)d_in[11];
    const float* pos_b  = (const float*)d_in[12];
    const float* ln2_g  = (const float*)d_in[13];
    const float* ln2_b  = (const float*)d_in[14];
    const float* Wm1    = (const float*)d_in[15];
    const float* bm1    = (const float*)d_in[16];
    const float* Wm2    = (const float*)d_in[17];
    const float* bm2    = (const float*)d_in[18];

    // d_ws: xt (bf16 residual stream), 50.3 MB (known-safe)
    ushort_t* xt = (ushort_t*)d_ws;
    // d_out scratch map (100.66 MB total, all dead before k4 writes):
    //   [0, 25165824)             xw (k2 input); per-chunk reused as z, then as hbuf
    //   [25165824, ..)            transposed weights
    //   [26935296, +18874368)     qkv chunk buffer (attention phase) == xn (MLP phase)
    //   [45809664, +2304)         bqkv f32[1152]
    ushort_t* scratch = (ushort_t*)d_out;
    ushort_t* xw    = scratch;
    ushort_t* Wqkvt = scratch + 25165824;
    ushort_t* Wot   = Wqkvt + 1152 * E_;
    ushort_t* Wm1t  = Wot  + E_ * E_;
    ushort_t* Wm2t  = Wm1t + E_ * HID_;
    ushort_t* qkvb  = scratch + 26935296;
    ushort_t* xn    = scratch + 26935296;
    float*    bqkv  = (float*)(scratch + 45809664);
    ushort_t* hbuf  = xw;   // alias: xw fully dead after attention phase

    const float qscale = 0.17677669529663687f;

    // weight transposes (f32 [K][N] -> bf16 [N][K]); q-scale folded
    wt_kernel<<<dim3(12, 12), 256, 0, stream>>>(Wq, Wqkvt, E_, E_, qscale);
    wt_kernel<<<dim3(12, 12), 256, 0, stream>>>(Wk, Wqkvt + 384 * E_, E_, E_, 1.f);
    wt_kernel<<<dim3(12, 12), 256, 0, stream>>>(Wv, Wqkvt + 768 * E_, E_, E_, 1.f);
    wt_kernel<<<dim3(12, 12), 256, 0, stream>>>(Wo, Wot, E_, E_, 1.f);
    wt_kernel<<<dim3(12, 48), 256, 0, stream>>>(Wm1, Wm1t, E_, HID_, 1.f);
    wt_kernel<<<dim3(48, 12), 256, 0, stream>>>(Wm2, Wm2t, HID_, E_, 1.f);
    bias_cat<<<9, 128, 0, stream>>>(bq, bk, bv, bqkv);

    k1_ln_window<<<dim3(P_ / 32, B_), 256, 0, stream>>>(x, ln1_g, ln1_b, xt, xw);

    // ---- attention phase: 4 chunks of 4 batches ----
    for (int mc = 0; mc < 4; ++mc){
        ushort_t* xwc = xw + (size_t)mc * MCH_ * E_;   // input rows; becomes z after qkv
        // QKV projection: [16384][1152]
        gemm128<12, E_, 1152, 0><<<dim3(9, MCH_ / 128), 256, 0, stream>>>(
            xwc, Wqkvt, bqkv, qkvb);
        // attention core -> z (overwrites consumed xw chunk)
        k2b_attn<<<dim3(NW_, 4, 3), 256, 0, stream>>>(qkvb, pos_b, mask, xwc);
        // Wo + window reverse + residual into xt
        gemm128<12, E_, E_, 3><<<dim3(3, MCH_ / 128), 256, 0, stream>>>(
            xwc, Wot, bo, xt + (size_t)mc * MCH_ * E_);
    }

    // ---- MLP phase: 4 chunks of 16384 rows ----
    for (int mc = 0; mc < 4; ++mc){
        ushort_t* xtc = xt + (size_t)mc * MCH_ * E_;
        ln2_apply<<<MCH_ / 64, 256, 0, stream>>>(xtc, ln2_g, ln2_b, xn);
        gemm128<12, E_, HID_, 1><<<dim3(HID_ / 128, MCH_ / 128), 256, 0, stream>>>(
            xn, Wm1t, bm1, hbuf);
        gemm128<48, HID_, E_, 2><<<dim3(E_ / 128, MCH_ / 128), 256, 0, stream>>>(
            hbuf, Wm2t, bm2, xtc);
    }

    k4_out<<<dim3(P_ / 32, E_ / 32, B_), 256, 0, stream>>>(xt, (float*)d_out);
}

// Round 5
// 717.814 us; speedup vs baseline: 2.4549x; 1.0047x over previous
//
#include <hip/hip_runtime.h>
#include <hip/hip_bf16.h>
#include <math.h>

// ---- problem dims ----
#define B_    16
#define E_    384
#define P_    4096
#define NW_   64
#define S_    64
#define H_    12
#define DH_   32
#define HID_  1536
#define T_    65536
#define SHIFT_ 4
#define MCH_  16384   // M-chunk rows (4 batches)

typedef unsigned short ushort_t;
typedef __attribute__((ext_vector_type(8))) __bf16 b8;
typedef __attribute__((ext_vector_type(8))) ushort_t u8v;
typedef __attribute__((ext_vector_type(4))) float f4;
typedef __attribute__((ext_vector_type(4))) unsigned u32x4;

__device__ __forceinline__ float u2f(ushort_t u){
    return __uint_as_float(((unsigned)u) << 16);
}
__device__ __forceinline__ ushort_t f2u(float f){
    union { __hip_bfloat16 h; ushort_t u; } cv;
    cv.h = __float2bfloat16(f);
    return cv.u;
}
__device__ __forceinline__ unsigned pack2(float lo, float hi){
    return (unsigned)f2u(lo) | ((unsigned)f2u(hi) << 16);
}
__device__ __forceinline__ float gelu_f(float v){
    return 0.5f * v * (1.0f + erff(v * 0.70710678118654752440f));
}

#define MFMA(a,b,c) __builtin_amdgcn_mfma_f32_16x16x32_bf16((a),(b),(c),0,0,0)

// async global->LDS, 16B per lane (per-lane lds ptr must be uniform+lane*16)
#define GL2LDS(gp, lp) \
    __builtin_amdgcn_global_load_lds((const __attribute__((address_space(1))) void*)(gp), \
                                     (__attribute__((address_space(3))) void*)(lp), 16, 0, 0)

// =====================================================================
// WT: transpose f32 [K][N] -> bf16 [N][K], optional scale fold
// =====================================================================
__global__ __launch_bounds__(256) void wt_kernel(
    const float* __restrict__ src, ushort_t* __restrict__ dst, int K, int N,
    float scale)
{
    __shared__ float t[32][33];
    const int k0 = blockIdx.x * 32, n0 = blockIdx.y * 32;
    const int c = threadIdx.x & 31, r = threadIdx.x >> 5;
    for (int rr = r; rr < 32; rr += 8)
        t[rr][c] = src[(size_t)(k0 + rr) * N + n0 + c];
    __syncthreads();
    for (int rr = r; rr < 32; rr += 8)
        dst[(size_t)(n0 + rr) * K + k0 + c] = f2u(t[c][rr] * scale);
}

// concat bias: [bq*scale | bk | bv] -> f32[1152]
__global__ __launch_bounds__(128) void bias_cat(
    const float* __restrict__ bq, const float* __restrict__ bk,
    const float* __restrict__ bv, float* __restrict__ o)
{
    const int i = blockIdx.x * 128 + threadIdx.x;
    float v;
    if (i < 384)      v = bq[i] * 0.17677669529663687f;
    else if (i < 768) v = bk[i - 384];
    else              v = bv[i - 768];
    o[i] = v;
}

// =====================================================================
// K1: x (B,E,P) f32 -> xt bf16 (B,P,E) + LN1 -> shift -> window -> xw
// Pass 1: 12 independent f4 loads/thread (max MLP), pure copy to bf16
// tile (stride 386, conflict-free), stats from f32 REGISTERS reduced via
// shuffle + tiny LDS. No dependent-load batching stalls.
// =====================================================================
__global__ __launch_bounds__(256) void k1_ln_window(
    const float* __restrict__ x, const float* __restrict__ g,
    const float* __restrict__ bt,
    ushort_t* __restrict__ xt, ushort_t* __restrict__ xw)
{
    __shared__ ushort_t tile[32][E_ + 2];        // bf16, stride 386
    __shared__ float redS[4][32], redQ[4][32];
    __shared__ float mu_s[32], rs_s[32];
    const int b = blockIdx.y, p0 = blockIdx.x * 32, tid = threadIdx.x;

    {
        const int pq = tid & 7, e00 = tid >> 3;      // p-quad, e-base 0..31
        const float* xp = x + ((size_t)b * E_ + e00) * P_ + p0 + pq * 4;
        f4 v[12];
#pragma unroll
        for (int i = 0; i < 12; ++i)
            v[i] = *(const f4*)(xp + (size_t)(i * 32) * P_);
        float s0 = 0.f, s1 = 0.f, s2 = 0.f, s3 = 0.f;
        float q0 = 0.f, q1 = 0.f, q2 = 0.f, q3 = 0.f;
#pragma unroll
        for (int i = 0; i < 12; ++i){
            const int e = e00 + i * 32;
            tile[pq * 4 + 0][e] = f2u(v[i][0]);
            tile[pq * 4 + 1][e] = f2u(v[i][1]);
            tile[pq * 4 + 2][e] = f2u(v[i][2]);
            tile[pq * 4 + 3][e] = f2u(v[i][3]);
            s0 += v[i][0]; q0 += v[i][0] * v[i][0];
            s1 += v[i][1]; q1 += v[i][1] * v[i][1];
            s2 += v[i][2]; q2 += v[i][2] * v[i][2];
            s3 += v[i][3]; q3 += v[i][3] * v[i][3];
        }
        // reduce over lanes with same pq within the wave (lane = pq + 8k)
#pragma unroll
        for (int m = 8; m < 64; m <<= 1){
            s0 += __shfl_xor(s0, m); q0 += __shfl_xor(q0, m);
            s1 += __shfl_xor(s1, m); q1 += __shfl_xor(q1, m);
            s2 += __shfl_xor(s2, m); q2 += __shfl_xor(q2, m);
            s3 += __shfl_xor(s3, m); q3 += __shfl_xor(q3, m);
        }
        const int lane = tid & 63, wvi = tid >> 6;
        if (lane < 8){
            redS[wvi][pq * 4 + 0] = s0; redQ[wvi][pq * 4 + 0] = q0;
            redS[wvi][pq * 4 + 1] = s1; redQ[wvi][pq * 4 + 1] = q1;
            redS[wvi][pq * 4 + 2] = s2; redQ[wvi][pq * 4 + 2] = q2;
            redS[wvi][pq * 4 + 3] = s3; redQ[wvi][pq * 4 + 3] = q3;
        }
    }
    __syncthreads();
    if (tid < 32){
        const float s  = redS[0][tid] + redS[1][tid] + redS[2][tid] + redS[3][tid];
        const float ss = redQ[0][tid] + redQ[1][tid] + redQ[2][tid] + redQ[3][tid];
        const float mu = s / E_;
        mu_s[tid] = mu;
        rs_s[tid] = rsqrtf(ss / E_ - mu * mu + 1e-5f);
    }
    __syncthreads();

    unsigned* xtu = (unsigned*)xt;
    unsigned* xwu = (unsigned*)xw;
    for (int it = 0; it < 24; ++it){
        const int idx = it * 256 + tid;
        const int pj = idx / 192, ep = idx - pj * 192;
        const int e  = ep * 2;
        const int p  = p0 + pj;
        const int d1 = p >> 6, d2 = p & 63;
        const int i_ = (d1 + 64 - SHIFT_) & 63;
        const int j_ = (d2 + 64 - SHIFT_) & 63;
        const int w  = ((i_ >> 3) << 3) + (j_ >> 3);
        const int sd = ((i_ & 7) << 3) + (j_ & 7);
        const size_t dstu = (((size_t)b * NW_ + w) * S_ + sd) * (E_ / 2);
        const size_t srcu = ((size_t)b * P_ + p) * (E_ / 2);
        const unsigned tv = *(const unsigned*)&tile[pj][e];
        xtu[srcu + ep] = tv;                      // xt = bf16(v) pair, verbatim
        const float v0 = u2f((ushort_t)tv), v1 = u2f((ushort_t)(tv >> 16));
        const float mu = mu_s[pj], rs = rs_s[pj];
        xwu[dstu + ep] = pack2((v0 - mu) * rs * g[e] + bt[e],
                               (v1 - mu) * rs * g[e + 1] + bt[e + 1]);
    }
}

// =====================================================================
// stage a 128x32 bf16 tile: global (row stride gs ushorts) -> LDS linear
// =====================================================================
__device__ __forceinline__ void stage_tile(const ushort_t* gsrc, int gs,
                                           ushort_t* ldst, int k0, int tid)
{
#pragma unroll
    for (int i = 0; i < 2; ++i){
        const int eid = i * 256 + tid;
        const int row = eid >> 2, kq = eid & 3;
        GL2LDS(gsrc + (size_t)row * gs + k0 + kq * 8, ldst + eid * 8);
    }
}

// =====================================================================
// gemm128: C = A[M][AS-K] @ Bm^T (Bm = [N][K] bf16) + bias, 128x128 tiles.
// XCD-bijective block swizzle: same-A-panel blocks land on one XCD's L2.
// MODE 0: store bf16 nontemporal (qkv projection, scale pre-folded)
// MODE 1: gelu, store bf16 nontemporal (mlp gemm1)
// MODE 2: gelu, residual RMW            (mlp gemm2)
// MODE 3: residual RMW with window-reverse row permutation (Wo)
// =====================================================================
template<int KST, int AS, int OS, int MODE>
__global__ __launch_bounds__(256, 4) void gemm128(
    const ushort_t* __restrict__ A, const ushort_t* __restrict__ Bm,
    const float* __restrict__ bias, ushort_t* __restrict__ out)
{
    __shared__ __align__(16) ushort_t lds[16384];
    const int tid = threadIdx.x, lane = tid & 63, wv = tid >> 6;
    const int l15 = lane & 15, l4 = lane >> 4;
    const int wr = wv >> 1, wc = wv & 1;

    // XCD-aware bijective remap (all grids have nwg % 8 == 0)
    const int gx = gridDim.x;
    const int nwg = gx * gridDim.y;
    const int d = blockIdx.y * gx + blockIdx.x;
    const int cpx = nwg >> 3;
    const int lb = (d & 7) * cpx + (d >> 3);
    const int n0 = (lb % gx) * 128;
    const size_t m0 = (size_t)(lb / gx) * 128;

    const ushort_t* Ag = A + m0 * AS;
    const ushort_t* Bg = Bm + (size_t)n0 * (KST * 32);

    f4 acc[4][4];
#pragma unroll
    for (int i = 0; i < 4; ++i)
#pragma unroll
        for (int j = 0; j < 4; ++j) acc[i][j] = (f4){0.f, 0.f, 0.f, 0.f};

    stage_tile(Ag, AS, lds, 0, tid);
    stage_tile(Bg, KST * 32, lds + 8192, 0, tid);
    __syncthreads();
    int buf = 0;
    for (int ks = 0; ks < KST; ++ks){
        if (ks < KST - 1){
            stage_tile(Ag, AS, lds + (buf ^ 1) * 4096, (ks + 1) * 32, tid);
            stage_tile(Bg, KST * 32, lds + 8192 + (buf ^ 1) * 4096, (ks + 1) * 32, tid);
        }
        const ushort_t* Al = lds + buf * 4096;
        const ushort_t* Bl = lds + 8192 + buf * 4096;
        b8 ax[4], aw[4];
#pragma unroll
        for (int f = 0; f < 4; ++f){
            ax[f] = *(const b8*)(Al + (wr * 64 + f * 16 + l15) * 32 + l4 * 8);
            aw[f] = *(const b8*)(Bl + (wc * 64 + f * 16 + l15) * 32 + l4 * 8);
        }
#pragma unroll
        for (int fm = 0; fm < 4; ++fm)
#pragma unroll
            for (int fn = 0; fn < 4; ++fn)
                acc[fm][fn] = MFMA(aw[fn], ax[fm], acc[fm][fn]);
        __syncthreads();
        buf ^= 1;
    }

    // epilogue via per-wave LDS bounce [32][72] -> coalesced b128
    ushort_t* bounce = lds + wv * 2304;
    const int l8r = lane >> 3, l8c = lane & 7;
#pragma unroll
    for (int hh = 0; hh < 2; ++hh){
#pragma unroll
        for (int f2 = 0; f2 < 2; ++f2){
            const int fm = hh * 2 + f2;
#pragma unroll
            for (int fn = 0; fn < 4; ++fn){
                const f4 v = acc[fm][fn];
                const f4 bb = *(const f4*)(bias + n0 + wc * 64 + fn * 16 + l4 * 4);
                uint2 pk;
                if (MODE == 1 || MODE == 2){
                    pk.x = pack2(gelu_f(v[0] + bb[0]), gelu_f(v[1] + bb[1]));
                    pk.y = pack2(gelu_f(v[2] + bb[2]), gelu_f(v[3] + bb[3]));
                } else {
                    pk.x = pack2(v[0] + bb[0], v[1] + bb[1]);
                    pk.y = pack2(v[2] + bb[2], v[3] + bb[3]);
                }
                *(uint2*)(bounce + (f2 * 16 + l15) * 72 + fn * 16 + l4 * 4) = pk;
            }
        }
#pragma unroll
        for (int i = 0; i < 4; ++i){
            const int br = i * 8 + l8r;
            const int grow = (int)m0 + wr * 64 + hh * 32 + br;
            const b8 yv = *(const b8*)(bounce + br * 72 + l8c * 8);
            size_t orow;
            if (MODE == 3){
                const int bl = grow >> 12, wn = (grow >> 6) & 63, sw = grow & 63;
                const int d1 = ((wn >> 3) * 8 + (sw >> 3) + SHIFT_) & 63;
                const int d2 = ((wn & 7) * 8 + (sw & 7) + SHIFT_) & 63;
                orow = ((size_t)bl << 12) + d1 * 64 + d2;
            } else {
                orow = (size_t)grow;
            }
            ushort_t* px = out + orow * OS + n0 + wc * 64 + l8c * 8;
            if (MODE >= 2){
                const b8 ov = *(const b8*)px;
                union { b8 v; unsigned u[4]; } o;
#pragma unroll
                for (int j = 0; j < 4; ++j)
                    o.u[j] = pack2((float)ov[2 * j] + (float)yv[2 * j],
                                   (float)ov[2 * j + 1] + (float)yv[2 * j + 1]);
                *(b8*)px = o.v;
            } else {
                // streaming output: don't evict the operand panels from L2
                union { b8 v; u32x4 q; } t; t.v = yv;
                __builtin_nontemporal_store(t.q, (u32x4*)px);
            }
        }
    }
}

// =====================================================================
// K2b: attention core only. qkv [rows][1152] chunk-local (q|k|v, q scaled),
// block = (window, batch-in-chunk, head-group of 4). z [rows][384] out.
// =====================================================================
__global__ __launch_bounds__(256) void k2b_attn(
    const ushort_t* __restrict__ qkv,
    const float* __restrict__ pb, const float* __restrict__ mk,
    ushort_t* __restrict__ z)
{
    __shared__ __align__(16) ushort_t q_lds[64 * 32];
    __shared__ __align__(16) ushort_t k_lds[64 * 32];
    __shared__ __align__(16) ushort_t vt_lds[32 * 72];
    __shared__ __align__(16) ushort_t P_lds[64 * 72];

    const int w = blockIdx.x, bl = blockIdx.y, hz = blockIdx.z;
    const int tid = threadIdx.x, lane = tid & 63, wv = tid >> 6;
    const int l15 = lane & 15, l4 = lane >> 4;
    const int rowbase = (bl * NW_ + w) * S_;

    // staging geometry: LDS unit tid holds row=tid>>2, global quad (tid&3)^((row>>1)&3)
    const int srow = tid >> 2, sqp = tid & 3;
    const int sfq = sqp ^ ((srow >> 1) & 3);
    const ushort_t* gql = qkv + (size_t)(rowbase + srow) * 1152 + sfq * 8;
    const ushort_t* gvl = qkv + (size_t)(rowbase + srow) * 1152 + 768 + sqp * 8;

    for (int hi = 0; hi < 4; ++hi){
        const int h = hz * 4 + hi;
        const int hb = h * 32;
        // ---- stage Q,K (swizzled source -> linear LDS), V (reg -> [d][t]) ----
        GL2LDS(gql + hb, q_lds + tid * 8);
        GL2LDS(gql + 384 + hb, k_lds + tid * 8);
        {
            const u8v vv = *(const u8v*)(gvl + hb);
#pragma unroll
            for (int j = 0; j < 8; ++j)
                vt_lds[(sqp * 8 + j) * 72 + srow] = vv[j];
        }
        __syncthreads();

        // ---- QK^T + bias + softmax ----
        {
            const int qr = wv * 16 + l15;
            const int uq = qr * 4 + (l4 ^ ((qr >> 1) & 3));
            const b8 qfrag = *(const b8*)(&q_lds[uq * 8]);
            f4 sacc[4];
#pragma unroll
            for (int nt = 0; nt < 4; ++nt){
                const int kr = nt * 16 + l15;
                const int uk = kr * 4 + (l4 ^ ((kr >> 1) & 3));
                const b8 kfrag = *(const b8*)(&k_lds[uk * 8]);
                f4 c = (f4){0.f, 0.f, 0.f, 0.f};
                c = MFMA(qfrag, kfrag, c);
                const int t = nt * 16 + l15;
#pragma unroll
                for (int r = 0; r < 4; ++r){
                    const int sw = wv * 16 + l4 * 4 + r;
                    c[r] += pb[((size_t)h * S_ + sw) * S_ + t]
                          + mk[((size_t)w * S_ + sw) * S_ + t];
                }
                sacc[nt] = c;
            }
#pragma unroll
            for (int r = 0; r < 4; ++r){
                float m = fmaxf(fmaxf(sacc[0][r], sacc[1][r]),
                                fmaxf(sacc[2][r], sacc[3][r]));
                m = fmaxf(m, __shfl_xor(m, 1));
                m = fmaxf(m, __shfl_xor(m, 2));
                m = fmaxf(m, __shfl_xor(m, 4));
                m = fmaxf(m, __shfl_xor(m, 8));
                const float e0 = expf(sacc[0][r] - m), e1 = expf(sacc[1][r] - m);
                const float e2 = expf(sacc[2][r] - m), e3 = expf(sacc[3][r] - m);
                float s = e0 + e1 + e2 + e3;
                s += __shfl_xor(s, 1); s += __shfl_xor(s, 2);
                s += __shfl_xor(s, 4); s += __shfl_xor(s, 8);
                const float inv = 1.f / s;
                const int row = wv * 16 + l4 * 4 + r;
                P_lds[row * 72 +      l15] = f2u(e0 * inv);
                P_lds[row * 72 + 16 + l15] = f2u(e1 * inv);
                P_lds[row * 72 + 32 + l15] = f2u(e2 * inv);
                P_lds[row * 72 + 48 + l15] = f2u(e3 * inv);
            }
        }

        // ---- PV -> z global ----
        {
            f4 zacc[2];
#pragma unroll
            for (int nt = 0; nt < 2; ++nt) zacc[nt] = (f4){0.f, 0.f, 0.f, 0.f};
#pragma unroll
            for (int kb = 0; kb < 2; ++kb){
                const b8 pfrag = *(const b8*)(&P_lds[(wv * 16 + l15) * 72 + kb * 32 + l4 * 8]);
#pragma unroll
                for (int nt = 0; nt < 2; ++nt){
                    const b8 vfrag = *(const b8*)(&vt_lds[(nt * 16 + l15) * 72 + kb * 32 + l4 * 8]);
                    zacc[nt] = MFMA(pfrag, vfrag, zacc[nt]);
                }
            }
#pragma unroll
            for (int nt = 0; nt < 2; ++nt)
#pragma unroll
                for (int r = 0; r < 4; ++r){
                    const int row = wv * 16 + l4 * 4 + r;
                    z[(size_t)(rowbase + row) * E_ + hb + nt * 16 + l15] = f2u(zacc[nt][r]);
                }
        }
        __syncthreads();
    }
}

// =====================================================================
// LN2 apply: xt chunk rows -> xn (chunk-local), bf16
// =====================================================================
__global__ __launch_bounds__(256) void ln2_apply(
    const ushort_t* __restrict__ xtc, const float* __restrict__ g2,
    const float* __restrict__ b2, ushort_t* __restrict__ xn)
{
    const int tid = threadIdx.x;
    const int lr = blockIdx.x * 64 + (tid >> 2), q = tid & 3;
    const ushort_t* rp = xtc + (size_t)lr * E_;
    b8 xv[12];
    float s = 0.f, ss = 0.f;
#pragma unroll
    for (int i = 0; i < 12; ++i){
        xv[i] = *(const b8*)(rp + q * 8 + i * 32);
#pragma unroll
        for (int j = 0; j < 8; ++j){ const float v = (float)xv[i][j]; s += v; ss += v * v; }
    }
    s += __shfl_xor(s, 1); ss += __shfl_xor(ss, 1);
    s += __shfl_xor(s, 2); ss += __shfl_xor(ss, 2);
    const float mu = s * (1.f / E_);
    const float rs = rsqrtf(ss * (1.f / E_) - mu * mu + 1e-5f);
    ushort_t* op = xn + (size_t)lr * E_;
#pragma unroll
    for (int i = 0; i < 12; ++i){
        const int e = q * 8 + i * 32;
        const f4 ga = *(const f4*)(g2 + e), gb = *(const f4*)(g2 + e + 4);
        const f4 ba = *(const f4*)(b2 + e), bb = *(const f4*)(b2 + e + 4);
        union { b8 v; unsigned u[4]; } o;
        o.u[0] = pack2(((float)xv[i][0] - mu) * rs * ga[0] + ba[0],
                       ((float)xv[i][1] - mu) * rs * ga[1] + ba[1]);
        o.u[1] = pack2(((float)xv[i][2] - mu) * rs * ga[2] + ba[2],
                       ((float)xv[i][3] - mu) * rs * ga[3] + ba[3]);
        o.u[2] = pack2(((float)xv[i][4] - mu) * rs * gb[0] + bb[0],
                       ((float)xv[i][5] - mu) * rs * gb[1] + bb[1]);
        o.u[3] = pack2(((float)xv[i][6] - mu) * rs * gb[2] + bb[2],
                       ((float)xv[i][7] - mu) * rs * gb[3] + bb[3]);
        *(b8*)(op + e) = o.v;
    }
}

// =====================================================================
// K4: xt bf16 (B,P,E) -> out f32 (B,E,P). Vectorized: b8 loads (16B),
// LDS transpose tile [32 e][68 p] (f4-aligned rows), f4 nt stores.
// =====================================================================
__global__ __launch_bounds__(256) void k4_out(
    const ushort_t* __restrict__ xt, float* __restrict__ out)
{
    __shared__ float tile[32][68];
    const int b = blockIdx.z, p0 = blockIdx.x * 64, e0 = blockIdx.y * 32;
    const int tid = threadIdx.x;
    {
        const int r = tid >> 2, c = tid & 3;       // r: p-row 0..63, c: e-oct
        const u8v v = *(const u8v*)(xt + ((size_t)b * P_ + p0 + r) * E_ + e0 + c * 8);
#pragma unroll
        for (int j = 0; j < 8; ++j)
            tile[c * 8 + j][r] = u2f(v[j]);
    }
    __syncthreads();
    {
        const int er = tid >> 3, pc = tid & 7;     // er: e-row 0..31, pc: p-oct
        float* op = out + ((size_t)b * E_ + e0 + er) * P_ + p0 + pc * 8;
        const f4 v0 = *(const f4*)&tile[er][pc * 8];
        const f4 v1 = *(const f4*)&tile[er][pc * 8 + 4];
        __builtin_nontemporal_store(v0, (f4*)op);
        __builtin_nontemporal_store(v1, (f4*)(op + 4));
    }
}

// =====================================================================
extern "C" void kernel_launch(void* const* d_in, const int* in_sizes, int n_in,
                              void* d_out, int out_size, void* d_ws, size_t ws_size,
                              hipStream_t stream)
{
    const float* x      = (const float*)d_in[0];
    const float* mask   = (const float*)d_in[1];
    const float* ln1_g  = (const float*)d_in[2];
    const float* ln1_b  = (const float*)d_in[3];
    const float* Wq     = (const float*)d_in[4];
    const float* bq     = (const float*)d_in[5];
    const float* Wk     = (const float*)d_in[6];
    const float* bk     = (const float*)d_in[7];
    const float* Wv     = (const float*)d_in[8];
    const float* bv     = (const float*)d_in[9];
    const float* Wo     = (const float*)d_in[10];
    const float* bo     = (const float*)d_in[11];
    const float* pos_b  = (const float*)d_in[12];
    const float* ln2_g  = (const float*)d_in[13];
    const float* ln2_b  = (const float*)d_in[14];
    const float* Wm1    = (const float*)d_in[15];
    const float* bm1    = (const float*)d_in[16];
    const float* Wm2    = (const float*)d_in[17];
    const float* bm2    = (const float*)d_in[18];

    // d_ws: xt (bf16 residual stream), 50.3 MB (known-safe)
    ushort_t* xt = (ushort_t*)d_ws;
    // d_out scratch map (100.66 MB total, all dead before k4 writes):
    //   [0, 25165824)             xw (k2 input); per-chunk reused as z, then as hbuf
    //   [25165824, ..)            transposed weights
    //   [26935296, +18874368)     qkv chunk buffer (attention phase) == xn (MLP phase)
    //   [45809664, +2304)         bqkv f32[1152]
    ushort_t* scratch = (ushort_t*)d_out;
    ushort_t* xw    = scratch;
    ushort_t* Wqkvt = scratch + 25165824;
    ushort_t* Wot   = Wqkvt + 1152 * E_;
    ushort_t* Wm1t  = Wot  + E_ * E_;
    ushort_t* Wm2t  = Wm1t + E_ * HID_;
    ushort_t* qkvb  = scratch + 26935296;
    ushort_t* xn    = scratch + 26935296;
    float*    bqkv  = (float*)(scratch + 45809664);
    ushort_t* hbuf  = xw;   // alias: xw fully dead after attention phase

    const float qscale = 0.17677669529663687f;

    // weight transposes (f32 [K][N] -> bf16 [N][K]); q-scale folded
    wt_kernel<<<dim3(12, 12), 256, 0, stream>>>(Wq, Wqkvt, E_, E_, qscale);
    wt_kernel<<<dim3(12, 12), 256, 0, stream>>>(Wk, Wqkvt + 384 * E_, E_, E_, 1.f);
    wt_kernel<<<dim3(12, 12), 256, 0, stream>>>(Wv, Wqkvt + 768 * E_, E_, E_, 1.f);
    wt_kernel<<<dim3(12, 12), 256, 0, stream>>>(Wo, Wot, E_, E_, 1.f);
    wt_kernel<<<dim3(12, 48), 256, 0, stream>>>(Wm1, Wm1t, E_, HID_, 1.f);
    wt_kernel<<<dim3(48, 12), 256, 0, stream>>>(Wm2, Wm2t, HID_, E_, 1.f);
    bias_cat<<<9, 128, 0, stream>>>(bq, bk, bv, bqkv);

    k1_ln_window<<<dim3(P_ / 32, B_), 256, 0, stream>>>(x, ln1_g, ln1_b, xt, xw);

    // ---- attention phase: 4 chunks of 4 batches ----
    for (int mc = 0; mc < 4; ++mc){
        ushort_t* xwc = xw + (size_t)mc * MCH_ * E_;   // input rows; becomes z after qkv
        // QKV projection: [16384][1152]
        gemm128<12, E_, 1152, 0><<<dim3(9, MCH_ / 128), 256, 0, stream>>>(
            xwc, Wqkvt, bqkv, qkvb);
        // attention core -> z (overwrites consumed xw chunk)
        k2b_attn<<<dim3(NW_, 4, 3), 256, 0, stream>>>(qkvb, pos_b, mask, xwc);
        // Wo + window reverse + residual into xt
        gemm128<12, E_, E_, 3><<<dim3(3, MCH_ / 128), 256, 0, stream>>>(
            xwc, Wot, bo, xt + (size_t)mc * MCH_ * E_);
    }

    // ---- MLP phase: 4 chunks of 16384 rows ----
    for (int mc = 0; mc < 4; ++mc){
        ushort_t* xtc = xt + (size_t)mc * MCH_ * E_;
        ln2_apply<<<MCH_ / 64, 256, 0, stream>>>(xtc, ln2_g, ln2_b, xn);
        gemm128<12, E_, HID_, 1><<<dim3(HID_ / 128, MCH_ / 128), 256, 0, stream>>>(
            xn, Wm1t, bm1, hbuf);
        gemm128<48, HID_, E_, 2><<<dim3(E_ / 128, MCH_ / 128), 256, 0, stream>>>(
            hbuf, Wm2t, bm2, xtc);
    }

    k4_out<<<dim3(P_ / 64, E_ / 32, B_), 256, 0, stream>>>(xt, (float*)d_out);
}